// Round 10
// baseline (507.988 us; speedup 1.0000x reference)
//
#include <hip/hip_runtime.h>
#include <hip/hip_cooperative_groups.h>

namespace cg = cooperative_groups;

#define NSEG 8
#define LSEG 32768
#define EPS_GN 1e-5f
#define KSCALE 0.005524271728019903f   // 1/sqrt(32768)
#define QSCALE 0.17677669529663687f    // 1/sqrt(32)
#define INVN 2.384185791015625e-07f    // 1/4194304
#define SOPITCH 260                     // sou pitch in shorts

typedef __attribute__((ext_vector_type(4))) float f32x4;
typedef __attribute__((ext_vector_type(8))) __bf16 bf16x8;
typedef __attribute__((ext_vector_type(4))) short s16x4;

#define MFMA32(A, B, C) __builtin_amdgcn_mfma_f32_16x16x32_bf16(A, B, C, 0, 0, 0)
#define MFMA16(A, B, C) __builtin_amdgcn_mfma_f32_16x16x16bf16_1k(A, B, C, 0, 0, 0)

static __device__ __forceinline__ unsigned short f2bf(float f) {
  unsigned int u = __float_as_uint(f);
  u += 0x7fffu + ((u >> 16) & 1u);
  return (unsigned short)(u >> 16);
}
static __device__ __forceinline__ float bf2f(unsigned short s) {
  return __uint_as_float(((unsigned int)s) << 16);
}
static __device__ __forceinline__ s16x4 pack4(float a, float b, float c, float d) {
  union { __bf16 h[4]; s16x4 s; } u;
  u.h[0] = (__bf16)a; u.h[1] = (__bf16)b; u.h[2] = (__bf16)c; u.h[3] = (__bf16)d;
  return u.s;
}
static __device__ __forceinline__ ushort4 cvt4(float4 v) {
  union { __bf16 h[4]; ushort4 u; } z;
  z.h[0] = (__bf16)v.x; z.h[1] = (__bf16)v.y; z.h[2] = (__bf16)v.z; z.h[3] = (__bf16)v.w;
  return z.u;
}

// ---- blocks 0..2047: GN1 stats partials + x->bf16 copy | 2048..2239: W_qkv -> WT bf16 [384][128]
__global__ __launch_bounds__(256) void k_pre(
    const float* __restrict__ x, float* __restrict__ part, unsigned short* __restrict__ xb,
    const float* __restrict__ W, const float* __restrict__ gn1w, unsigned short* __restrict__ WT)
{
  const int t = threadIdx.x;
  if (blockIdx.x >= 2048) {
    int idx = (blockIdx.x - 2048) * 256 + t;   // 49152 total
    int n = idx >> 7, ch = idx & 127;
    WT[idx] = f2bf(gn1w[ch] * W[ch * 384 + n]);
    return;
  }
  const int c = blockIdx.x;                    // 256 blocks/segment, 128 points each
  const float4* xp = (const float4*)x + (size_t)c * 4096;
  ushort4* xo = (ushort4*)xb + (size_t)c * 4096;
  float s = 0.f, q = 0.f;
  #pragma unroll
  for (int i = 0; i < 16; ++i) {
    float4 v = xp[t + i * 256];
    s += v.x + v.y + v.z + v.w;
    q += v.x*v.x + v.y*v.y + v.z*v.z + v.w*v.w;
    xo[t + i * 256] = cvt4(v);
  }
  #pragma unroll
  for (int o = 1; o < 64; o <<= 1) { s += __shfl_xor(s, o); q += __shfl_xor(q, o); }
  __shared__ float red[8];
  int wave = t >> 6, lane = t & 63;
  if (lane == 0) { red[wave*2] = s; red[wave*2+1] = q; }
  __syncthreads();
  if (t == 0) {
    part[c*2]   = red[0] + red[2] + red[4] + red[6];
    part[c*2+1] = red[1] + red[3] + red[5] + red[7];
  }
}

// ---- once per segment: finalize stats1 + fold GN1 bias through all 384 W columns + alpha scales
__global__ __launch_bounds__(384) void k_prep2(
    const float* __restrict__ part, const float* __restrict__ Wqkv,
    const float* __restrict__ gn1w, const float* __restrict__ gn1b,
    float* __restrict__ biasv, float* __restrict__ alpha)
{
  __shared__ float red[8];
  __shared__ float sm[2];
  const int seg = blockIdx.x, t = threadIdx.x;   // 384 threads
  const int wave = t >> 6, lane = t & 63;
  if (t < 256) {
    float s = part[(seg*256 + t)*2], q = part[(seg*256 + t)*2 + 1];
    #pragma unroll
    for (int o = 1; o < 64; o <<= 1) { s += __shfl_xor(s, o); q += __shfl_xor(q, o); }
    if (lane == 0) { red[wave*2] = s; red[wave*2+1] = q; }
  }
  __syncthreads();
  if (t == 0) {
    float s = red[0] + red[2] + red[4] + red[6];
    float q = red[1] + red[3] + red[5] + red[7];
    float mu = s * INVN;
    float var = q * INVN - mu * mu;
    float rs = rsqrtf(var + EPS_GN);
    sm[0] = mu * rs; sm[1] = rs;
  }
  __syncthreads();
  const float mu_rs = sm[0], rs = sm[1];
  float s = 0.f;
  for (int ch = 0; ch < 128; ++ch)
    s += (gn1b[ch] - mu_rs * gn1w[ch]) * Wqkv[ch * 384 + t];
  float scale = (t < 128) ? QSCALE : ((t < 256) ? KSCALE : 1.f);
  biasv[seg*384 + t] = s * scale;
  if (t == 0) {
    alpha[seg*4]   = rs * QSCALE;
    alpha[seg*4+1] = rs * KSCALE;
    alpha[seg*4+2] = rs;
  }
}

// ======================= phase bodies as macros (shared by coop + fallback) =======================

#define KV_BODY(XB, WT, BIASV, ALPHA, SUME_P, CTX_P, BID)                                  \
{                                                                                           \
  const int seg_ = (BID) >> 6, sub_ = (BID) & 63;                                           \
  const float alk = (ALPHA)[seg_*4 + 1], alv = (ALPHA)[seg_*4 + 2];                         \
  const float ck0 = (BIASV)[seg_*384 + 128 + h*32 + lm];                                    \
  const float ck1 = (BIASV)[seg_*384 + 128 + h*32 + 16 + lm];                               \
  const float cv0 = (BIASV)[seg_*384 + 256 + h*32 + lm];                                    \
  const float cv1 = (BIASV)[seg_*384 + 256 + h*32 + 16 + lm];                               \
  bf16x8 wk[2][4], wv[2][4];                                                                \
  _Pragma("unroll")                                                                         \
  for (int nt = 0; nt < 2; ++nt)                                                            \
    _Pragma("unroll")                                                                       \
    for (int kk = 0; kk < 4; ++kk) {                                                        \
      int row = h*32 + nt*16 + lm;                                                          \
      wk[nt][kk] = *(const bf16x8*)&(WT)[(row + 128) * 128 + kk*32 + lg*8];                 \
      wv[nt][kk] = *(const bf16x8*)&(WT)[(row + 256) * 128 + kk*32 + lg*8];                 \
    }                                                                                       \
  f32x4 ctx00 = {0,0,0,0}, ctx01 = {0,0,0,0}, ctx10 = {0,0,0,0}, ctx11 = {0,0,0,0};         \
  float se0 = 0.f, se1 = 0.f;                                                               \
  const unsigned short* xw = (XB) + (size_t)(seg_ * LSEG + sub_*512 + lm) * 128 + lg*8;     \
  bf16x8 sA[4], sB[4];                                                                      \
  KISSUE(sA, 0);                                                                            \
  _Pragma("unroll 1")                                                                       \
  for (int it = 0; it < 32; it += 2) {                                                      \
    KISSUE(sB, it + 1);                                                                     \
    KCOMPUTE(sA);                                                                           \
    if (it + 2 < 32) KISSUE(sA, it + 2);                                                    \
    KCOMPUTE(sB);                                                                           \
  }                                                                                         \
  se0 += __shfl_xor(se0, 16); se0 += __shfl_xor(se0, 32);                                   \
  se1 += __shfl_xor(se1, 16); se1 += __shfl_xor(se1, 32);                                   \
  if (lane < 16) {                                                                          \
    (SUME_P)[(size_t)(BID)*128 + h*32 + lm]      = se0;                                     \
    (SUME_P)[(size_t)(BID)*128 + h*32 + 16 + lm] = se1;                                     \
  }                                                                                         \
  float* cp = (CTX_P) + (size_t)(BID)*4096 + h*1024;                                        \
  _Pragma("unroll")                                                                         \
  for (int r = 0; r < 4; ++r) {                                                             \
    cp[(lg*4 + r)*32      + lm]      = ctx00[r];                                            \
    cp[(lg*4 + r)*32      + 16 + lm] = ctx01[r];                                            \
    cp[(16 + lg*4 + r)*32 + lm]      = ctx10[r];                                            \
    cp[(16 + lg*4 + r)*32 + 16 + lm] = ctx11[r];                                            \
  }                                                                                         \
}

#define KISSUE(S, IT) {                                             \
    const unsigned short* p_ = xw + (size_t)((IT) * 16) * 128;      \
    S[0] = *(const bf16x8*)(p_);                                    \
    S[1] = *(const bf16x8*)(p_ + 32);                               \
    S[2] = *(const bf16x8*)(p_ + 64);                               \
    S[3] = *(const bf16x8*)(p_ + 96); }

#define KCOMPUTE(S) {                                                                   \
    f32x4 ka0 = {0,0,0,0}, ka1 = {0,0,0,0}, va0 = {0,0,0,0}, va1 = {0,0,0,0};           \
    _Pragma("unroll") for (int kk = 0; kk < 4; ++kk) {                                  \
      ka0 = MFMA32(S[kk], wk[0][kk], ka0);                                              \
      ka1 = MFMA32(S[kk], wk[1][kk], ka1);                                              \
    }                                                                                   \
    _Pragma("unroll") for (int kk = 0; kk < 4; ++kk) {                                  \
      va0 = MFMA32(S[kk], wv[0][kk], va0);                                              \
      va1 = MFMA32(S[kk], wv[1][kk], va1);                                              \
    }                                                                                   \
    float e_[8];                                                                        \
    _Pragma("unroll") for (int r = 0; r < 4; ++r) {                                     \
      e_[r]     = __expf(fmaf(ka0[r], alk, ck0));                                       \
      e_[4 + r] = __expf(fmaf(ka1[r], alk, ck1));                                       \
    }                                                                                   \
    se0 += (e_[0] + e_[1]) + (e_[2] + e_[3]);                                           \
    se1 += (e_[4] + e_[5]) + (e_[6] + e_[7]);                                           \
    s16x4 E0 = pack4(e_[0], e_[1], e_[2], e_[3]);                                       \
    s16x4 E1 = pack4(e_[4], e_[5], e_[6], e_[7]);                                       \
    s16x4 V0 = pack4(fmaf(va0[0], alv, cv0), fmaf(va0[1], alv, cv0),                    \
                     fmaf(va0[2], alv, cv0), fmaf(va0[3], alv, cv0));                   \
    s16x4 V1 = pack4(fmaf(va1[0], alv, cv1), fmaf(va1[1], alv, cv1),                    \
                     fmaf(va1[2], alv, cv1), fmaf(va1[3], alv, cv1));                   \
    ctx00 = MFMA16(E0, V0, ctx00);                                                      \
    ctx01 = MFMA16(E0, V1, ctx01);                                                      \
    ctx10 = MFMA16(E1, V0, ctx10);                                                      \
    ctx11 = MFMA16(E1, V1, ctx11); }

#define WC_BODY(SUME_P, CTX_P, WOUT, WCT, B, SCTX, SSE)                                 \
{                                                                                        \
  const int seg_ = (B) >> 5, head_ = ((B) >> 3) & 3, ocg_ = (B) & 7;                     \
  float acc[4] = {0.f, 0.f, 0.f, 0.f};                                                  \
  for (int j = 0; j < 64; ++j) {                                                        \
    const float* cp = (CTX_P) + (size_t)(seg_*64 + j)*4096 + head_*1024;                 \
    _Pragma("unroll")                                                                    \
    for (int e = 0; e < 4; ++e) acc[e] += cp[t + e*256];                                 \
  }                                                                                      \
  if (t < 32) {                                                                          \
    float s = 0.f;                                                                       \
    for (int j = 0; j < 64; ++j) s += (SUME_P)[(size_t)(seg_*64 + j)*128 + head_*32 + t];\
    (SSE)[t] = s;                                                                        \
  }                                                                                      \
  _Pragma("unroll")                                                                      \
  for (int e = 0; e < 4; ++e) (SCTX)[t + e*256] = acc[e];                                \
  __syncthreads();                                                                       \
  _Pragma("unroll")                                                                      \
  for (int e = 0; e < 2; ++e) {                                                          \
    int idx = t + e*256;                                                                 \
    int kc = idx >> 4, ocl = idx & 15;                                                   \
    int oc = ocg_*16 + ocl;                                                              \
    float s = 0.f;                                                                       \
    _Pragma("unroll")                                                                    \
    for (int vc = 0; vc < 32; ++vc)                                                      \
      s += (SCTX)[kc*32 + vc] * (WOUT)[(head_*32 + vc)*128 + oc];                        \
    (WCT)[((size_t)seg_*128 + oc)*128 + head_*32 + kc] = f2bf(s / (SSE)[kc]);            \
  }                                                                                      \
}

#define LOADXF(IT) {                                                 \
    const unsigned short* p_ = xw + (size_t)((IT) * 16) * 128;       \
    xf0 = *(const bf16x8*)(p_);                                      \
    xf1 = *(const bf16x8*)(p_ + 32);                                 \
    xf2 = *(const bf16x8*)(p_ + 64);                                 \
    xf3 = *(const bf16x8*)(p_ + 96); }

#define SM2P(D) {                                                                       \
    f32x4 qa0 = {0,0,0,0}, qa1 = {0,0,0,0};                                             \
    qa0 = MFMA32(wq[0][0], xf0, qa0); qa1 = MFMA32(wq[1][0], xf0, qa1);                 \
    qa0 = MFMA32(wq[0][1], xf1, qa0); qa1 = MFMA32(wq[1][1], xf1, qa1);                 \
    qa0 = MFMA32(wq[0][2], xf2, qa0); qa1 = MFMA32(wq[1][2], xf2, qa1);                 \
    qa0 = MFMA32(wq[0][3], xf3, qa0); qa1 = MFMA32(wq[1][3], xf3, qa1);                 \
    float a_[8];                                                                        \
    _Pragma("unroll") for (int r = 0; r < 4; ++r) {                                     \
      a_[r]     = fmaf(qa0[r], alq, ((const float*)&cq0)[r]);                           \
      a_[4 + r] = fmaf(qa1[r], alq, ((const float*)&cq1)[r]);                           \
    }                                                                                   \
    float m_ = a_[0];                                                                   \
    _Pragma("unroll") for (int i = 1; i < 8; ++i) m_ = fmaxf(m_, a_[i]);                \
    m_ = fmaxf(m_, __shfl_xor(m_, 16));                                                 \
    m_ = fmaxf(m_, __shfl_xor(m_, 32));                                                 \
    float s_ = 0.f;                                                                     \
    _Pragma("unroll") for (int i = 0; i < 8; ++i) { a_[i] = __expf(a_[i] - m_); s_ += a_[i]; } \
    s_ += __shfl_xor(s_, 16);                                                           \
    s_ += __shfl_xor(s_, 32);                                                           \
    float inv_ = 1.f / s_;                                                              \
    *(s16x4*)&pbuf[D][(w*2)*256 + lane*4]     = pack4(a_[0]*inv_, a_[1]*inv_, a_[2]*inv_, a_[3]*inv_); \
    *(s16x4*)&pbuf[D][(w*2 + 1)*256 + lane*4] = pack4(a_[4]*inv_, a_[5]*inv_, a_[6]*inv_, a_[7]*inv_); }

#define OUT_BODY(XB, WT, BIASV, ALPHA, WCT, PART2, OUTM, BID, PBUF_UNUSED)              \
{                                                                                        \
  const int seg_ = (BID) >> 6;                                                          \
  const size_t cb = (size_t)(BID) * 512;                                                \
  const float alq = (ALPHA)[seg_*4];                                                    \
  const float4 cq0 = *(const float4*)&(BIASV)[seg_*384 + w*32 + lg*4];                  \
  const float4 cq1 = *(const float4*)&(BIASV)[seg_*384 + w*32 + 16 + lg*4];             \
  bf16x8 wq[2][4];                                                                      \
  _Pragma("unroll")                                                                     \
  for (int nt = 0; nt < 2; ++nt)                                                        \
    _Pragma("unroll")                                                                   \
    for (int kk = 0; kk < 4; ++kk)                                                      \
      wq[nt][kk] = *(const bf16x8*)&(WT)[(w*32 + nt*16 + lm) * 128 + kk*32 + lg*8];     \
  s16x4 wc[2][8];                                                                       \
  _Pragma("unroll")                                                                     \
  for (int o = 0; o < 2; ++o)                                                           \
    _Pragma("unroll")                                                                   \
    for (int kt = 0; kt < 8; ++kt)                                                      \
      wc[o][kt] = *(const s16x4*)&(WCT)[((size_t)seg_*128 + (w*32 + o*16 + lm))*128 + kt*16 + lg*4]; \
  const unsigned short* xw = (XB) + (cb + lm) * 128 + lg*8;                             \
  float ssum = 0.f, ssq = 0.f;                                                          \
  bf16x8 xf0, xf1, xf2, xf3;                                                            \
  LOADXF(0);                                                                            \
  SM2P(0);                                                                              \
  _Pragma("unroll 1")                                                                   \
  for (int ia = 0; ia < 32; ++ia) {                                                     \
    const int d = ia & 1;                                                               \
    __syncthreads();                                                                    \
    if (ia + 1 < 32) LOADXF(ia + 1);                                                    \
    f32x4 acc0 = {0,0,0,0}, acc1 = {0,0,0,0};                                           \
    _Pragma("unroll")                                                                   \
    for (int kt = 0; kt < 8; ++kt) {                                                    \
      s16x4 pk = *(const s16x4*)&pbuf[d][kt*256 + lane*4];                              \
      acc0 = MFMA16(wc[0][kt], pk, acc0);                                               \
      acc1 = MFMA16(wc[1][kt], pk, acc1);                                               \
    }                                                                                   \
    if (ia > 0) {                                                                       \
      _Pragma("unroll")                                                                 \
      for (int j = 0; j < 2; ++j) {                                                     \
        int f = t + j*256;                                                              \
        int pt = f >> 5, cc = f & 31;                                                   \
        ((ushort4*)(OUTM))[(cb + (size_t)(ia-1)*16 + pt)*32 + cc] =                     \
            *(const ushort4*)&sou[d^1][pt*SOPITCH + cc*4];                              \
      }                                                                                 \
    }                                                                                   \
    _Pragma("unroll")                                                                   \
    for (int r = 0; r < 4; ++r) {                                                       \
      ssum += acc0[r] + acc1[r];                                                        \
      ssq  += acc0[r]*acc0[r] + acc1[r]*acc1[r];                                        \
    }                                                                                   \
    {                                                                                   \
      unsigned short* dst = &sou[d][lm*SOPITCH + w*32 + lg*4];                          \
      dst[0] = f2bf(acc0[0]); dst[1] = f2bf(acc0[1]);                                   \
      dst[2] = f2bf(acc0[2]); dst[3] = f2bf(acc0[3]);                                   \
      dst += 16;                                                                        \
      dst[0] = f2bf(acc1[0]); dst[1] = f2bf(acc1[1]);                                   \
      dst[2] = f2bf(acc1[2]); dst[3] = f2bf(acc1[3]);                                   \
    }                                                                                   \
    if (ia + 1 < 32) SM2P(d ^ 1);                                                       \
  }                                                                                     \
  __syncthreads();                                                                      \
  _Pragma("unroll")                                                                     \
  for (int j = 0; j < 2; ++j) {                                                         \
    int f = t + j*256;                                                                  \
    int pt = f >> 5, cc = f & 31;                                                       \
    ((ushort4*)(OUTM))[(cb + (size_t)31*16 + pt)*32 + cc] =                             \
        *(const ushort4*)&sou[1][pt*SOPITCH + cc*4];                                    \
  }                                                                                     \
  _Pragma("unroll")                                                                     \
  for (int o = 1; o < 64; o <<= 1) { ssum += __shfl_xor(ssum, o); ssq += __shfl_xor(ssq, o); } \
  if (lane == 0) { red8[w*2] = ssum; red8[w*2+1] = ssq; }                               \
  __syncthreads();                                                                      \
  if (t == 0) {                                                                         \
    (PART2)[(BID)*2]   = red8[0] + red8[2] + red8[4] + red8[6];                         \
    (PART2)[(BID)*2+1] = red8[1] + red8[3] + red8[5] + red8[7];                         \
  }                                                                                     \
}

// ======================= cooperative fused kernel: KV -> WC -> OUT -> FIN =======================
__global__ __launch_bounds__(256, 2) void k_main(
    const unsigned short* __restrict__ xb, const unsigned short* __restrict__ WT,
    const float* __restrict__ biasv, const float* __restrict__ alpha,
    const float* __restrict__ Wout,
    float* __restrict__ sume_p, float* __restrict__ ctx_p, unsigned short* __restrict__ WcT,
    float* __restrict__ part2, unsigned short* __restrict__ outm,
    const float* __restrict__ gn2w, const float* __restrict__ gn2b, float* __restrict__ y)
{
  __shared__ float red8[8];
  __shared__ float sm2[2];
  __shared__ float sctx[1024];
  __shared__ float sse[32];
  __shared__ __attribute__((aligned(16))) short pbuf[2][8 * 256];
  __shared__ __attribute__((aligned(16))) unsigned short sou[2][16 * SOPITCH];

  const int t = threadIdx.x;
  const int w = t >> 6, h = w, lane = t & 63;
  const int lm = lane & 15, lg = lane >> 4;
  const int bid = blockIdx.x;               // 512

  // ---- phase KV
  KV_BODY(xb, WT, biasv, alpha, sume_p, ctx_p, bid)
  __threadfence();
  cg::this_grid().sync();

  // ---- phase WC (blocks 0..255)
  if (bid < 256) {
    WC_BODY(sume_p, ctx_p, Wout, WcT, bid, sctx, sse)
  }
  __threadfence();
  cg::this_grid().sync();

  // ---- phase OUT
  OUT_BODY(xb, WT, biasv, alpha, WcT, part2, outm, bid, pbuf)
  __threadfence();
  cg::this_grid().sync();

  // ---- phase FIN: stats2 + GN2 + residual over own chunk
  {
    float s = part2[t*2] + part2[(t+256)*2];
    float q = part2[t*2+1] + part2[(t+256)*2+1];
    #pragma unroll
    for (int o = 1; o < 64; o <<= 1) { s += __shfl_xor(s, o); q += __shfl_xor(q, o); }
    if (lane == 0) { red8[w*2] = s; red8[w*2+1] = q; }
    __syncthreads();
    if (t == 0) {
      float ss = red8[0] + red8[2] + red8[4] + red8[6];
      float qq = red8[1] + red8[3] + red8[5] + red8[7];
      float mu = ss * INVN;
      float var = qq * INVN - mu * mu;
      sm2[0] = mu; sm2[1] = rsqrtf(var + EPS_GN);
    }
    __syncthreads();
    const float mu = sm2[0], rs = sm2[1];
    const int c4 = t & 31;
    const float4 w4 = *(const float4*)&gn2w[c4*4];
    const float4 g4 = *(const float4*)&gn2b[c4*4];
    const size_t base = (size_t)bid * 16384;     // 512 pts * 32 ushort4
    const ushort4* xp = (const ushort4*)xb + base;
    const ushort4* op = (const ushort4*)outm + base;
    float4* yp = (float4*)y + base;
    #pragma unroll 4
    for (int i = 0; i < 64; ++i) {
      int f = t + i * 256;
      ushort4 xv = xp[f];
      ushort4 ov = op[f];
      float4 r;
      r.x = (bf2f(ov.x) - mu) * rs * w4.x + g4.x + bf2f(xv.x);
      r.y = (bf2f(ov.y) - mu) * rs * w4.y + g4.y + bf2f(xv.y);
      r.z = (bf2f(ov.z) - mu) * rs * w4.z + g4.z + bf2f(xv.z);
      r.w = (bf2f(ov.w) - mu) * rs * w4.w + g4.w + bf2f(xv.w);
      yp[f] = r;
    }
  }
}

// ======================= fallback kernels (r9 path) =======================
__global__ __launch_bounds__(256, 2) void k_kv(
    const unsigned short* __restrict__ xb, const unsigned short* __restrict__ WT,
    const float* __restrict__ biasv, const float* __restrict__ alpha,
    float* __restrict__ sume_p, float* __restrict__ ctx_p)
{
  const int t = threadIdx.x;
  const int h = t >> 6, lane = t & 63;
  const int lm = lane & 15, lg = lane >> 4;
  KV_BODY(xb, WT, biasv, alpha, sume_p, ctx_p, (int)blockIdx.x)
}

__global__ __launch_bounds__(256) void k_wc(
    const float* __restrict__ sume_p, const float* __restrict__ ctx_p,
    const float* __restrict__ Wout, unsigned short* __restrict__ WcT)
{
  __shared__ float sctx[1024];
  __shared__ float sse[32];
  const int t = threadIdx.x;
  WC_BODY(sume_p, ctx_p, Wout, WcT, (int)blockIdx.x, sctx, sse)
}

__global__ __launch_bounds__(256, 2) void k_out3(
    const unsigned short* __restrict__ xb, const unsigned short* __restrict__ WT,
    const float* __restrict__ biasv, const float* __restrict__ alpha,
    const unsigned short* __restrict__ WcT,
    float* __restrict__ part2, unsigned short* __restrict__ outm)
{
  __shared__ float red8[8];
  __shared__ __attribute__((aligned(16))) short pbuf[2][8 * 256];
  __shared__ __attribute__((aligned(16))) unsigned short sou[2][16 * SOPITCH];
  const int t = threadIdx.x;
  const int w = t >> 6, lane = t & 63;
  const int lm = lane & 15, lg = lane >> 4;
  OUT_BODY(xb, WT, biasv, alpha, WcT, part2, outm, (int)blockIdx.x, pbuf)
}

__global__ __launch_bounds__(256) void k_fin(
    const unsigned short* __restrict__ xb, const unsigned short* __restrict__ out_ws,
    const float* __restrict__ part2, const float* __restrict__ gn2w, const float* __restrict__ gn2b,
    float* __restrict__ y)
{
  __shared__ float sm[2];
  const int t = threadIdx.x;
  const int b = blockIdx.x >> 8, blk = blockIdx.x & 255;
  if (t < 64) {
    float s = part2[(b*64 + t)*2], q = part2[(b*64 + t)*2 + 1];
    #pragma unroll
    for (int o = 1; o < 64; o <<= 1) { s += __shfl_xor(s, o); q += __shfl_xor(q, o); }
    if (t == 0) {
      float mu = s * INVN;
      float var = q * INVN - mu * mu;
      sm[0] = mu; sm[1] = rsqrtf(var + EPS_GN);
    }
  }
  __syncthreads();
  const float mu = sm[0], rs = sm[1];
  const int c4 = t & 31;
  const float4 w4 = *(const float4*)&gn2w[c4*4];
  const float4 g4 = *(const float4*)&gn2b[c4*4];
  const size_t base = (size_t)b * 1048576 + (size_t)blk * 4096;
  const ushort4* xp = (const ushort4*)xb + base;
  const ushort4* op = (const ushort4*)out_ws + base;
  float4* yp = (float4*)y + base;
  #pragma unroll
  for (int i = 0; i < 16; ++i) {
    int f = t + i * 256;
    ushort4 xv = xp[f];
    ushort4 ov = op[f];
    float4 r;
    r.x = (bf2f(ov.x) - mu) * rs * w4.x + g4.x + bf2f(xv.x);
    r.y = (bf2f(ov.y) - mu) * rs * w4.y + g4.y + bf2f(xv.y);
    r.z = (bf2f(ov.z) - mu) * rs * w4.z + g4.z + bf2f(xv.z);
    r.w = (bf2f(ov.w) - mu) * rs * w4.w + g4.w + bf2f(xv.w);
    yp[f] = r;
  }
}

extern "C" void kernel_launch(void* const* d_in, const int* in_sizes, int n_in,
                              void* d_out, int out_size, void* d_ws, size_t ws_size,
                              hipStream_t stream) {
  const float* x    = (const float*)d_in[0];
  const float* gn1w = (const float*)d_in[1];
  const float* gn1b = (const float*)d_in[2];
  const float* Wqkv = (const float*)d_in[3];
  const float* Wout = (const float*)d_in[4];
  const float* gn2w = (const float*)d_in[5];
  const float* gn2b = (const float*)d_in[6];
  float* y = (float*)d_out;
  char* ws = (char*)d_ws;

  float*          part   = (float*)(ws + 0);                 // 2048*2 f32
  float*          part2  = (float*)(ws + 16384);             // 512*2 f32
  unsigned short* WT     = (unsigned short*)(ws + 24576);    // 384*128 bf16
  unsigned short* WcT    = (unsigned short*)(ws + 122880);   // 8*128*128 bf16
  float*          biasv  = (float*)(ws + 385024);            // 8*384 f32
  float*          alphav = (float*)(ws + 397312);            // 8*4 f32
  float*          sume_p = (float*)(ws + 401408);            // 512*128 f32
  float*          ctx_p  = (float*)(ws + 663552);            // 512*4096 f32
  unsigned short* xb     = (unsigned short*)(ws + 9052160);  // 67108864
  unsigned short* outm   = (unsigned short*)(ws + 76161024); // 67108864

  hipLaunchKernelGGL(k_pre,   dim3(2240), dim3(256), 0, stream, x, part, xb, Wqkv, gn1w, WT);
  hipLaunchKernelGGL(k_prep2, dim3(8),    dim3(384), 0, stream, part, Wqkv, gn1w, gn1b, biasv, alphav);

  const unsigned short* xb_c  = xb;
  const unsigned short* WT_c  = WT;
  const float* biasv_c = biasv;
  const float* alphav_c = alphav;
  unsigned short* WcT_m = WcT;
  void* args[] = {
    (void*)&xb_c, (void*)&WT_c, (void*)&biasv_c, (void*)&alphav_c, (void*)&Wout,
    (void*)&sume_p, (void*)&ctx_p, (void*)&WcT_m, (void*)&part2, (void*)&outm,
    (void*)&gn2w, (void*)&gn2b, (void*)&y
  };
  hipError_t ce = hipLaunchCooperativeKernel((void*)k_main, dim3(512), dim3(256),
                                             args, 0, stream);
  if (ce != hipSuccess) {
    hipLaunchKernelGGL(k_kv,   dim3(512),  dim3(256), 0, stream, xb, WT, biasv, alphav, sume_p, ctx_p);
    hipLaunchKernelGGL(k_wc,   dim3(256),  dim3(256), 0, stream, sume_p, ctx_p, Wout, WcT);
    hipLaunchKernelGGL(k_out3, dim3(512),  dim3(256), 0, stream, xb, WT, biasv, alphav, WcT, part2, outm);
    hipLaunchKernelGGL(k_fin,  dim3(2048), dim3(256), 0, stream, xb, outm, part2, gn2w, gn2b, y);
  }
}

// Round 11
// 223.240 us; speedup vs baseline: 2.2755x; 2.2755x over previous
//
#include <hip/hip_runtime.h>

#define NSEG 8
#define LSEG 32768
#define EPS_GN 1e-5f
#define KSCALE 0.005524271728019903f   // 1/sqrt(32768)
#define QSCALE 0.17677669529663687f    // 1/sqrt(32)
#define INVN 2.384185791015625e-07f    // 1/4194304
#define SOPITCH 260                     // sou pitch in shorts

typedef __attribute__((ext_vector_type(4))) float f32x4;
typedef __attribute__((ext_vector_type(8))) __bf16 bf16x8;
typedef __attribute__((ext_vector_type(4))) short s16x4;

#define MFMA32(A, B, C) __builtin_amdgcn_mfma_f32_16x16x32_bf16(A, B, C, 0, 0, 0)
#define MFMA16(A, B, C) __builtin_amdgcn_mfma_f32_16x16x16bf16_1k(A, B, C, 0, 0, 0)

static __device__ __forceinline__ unsigned short f2bf(float f) {
  unsigned int u = __float_as_uint(f);
  u += 0x7fffu + ((u >> 16) & 1u);
  return (unsigned short)(u >> 16);
}
static __device__ __forceinline__ float bf2f(unsigned short s) {
  return __uint_as_float(((unsigned int)s) << 16);
}
static __device__ __forceinline__ s16x4 pack4(float a, float b, float c, float d) {
  union { __bf16 h[4]; s16x4 s; } u;
  u.h[0] = (__bf16)a; u.h[1] = (__bf16)b; u.h[2] = (__bf16)c; u.h[3] = (__bf16)d;
  return u.s;
}
static __device__ __forceinline__ ushort4 cvt4(float4 v) {
  union { __bf16 h[4]; ushort4 u; } z;
  z.h[0] = (__bf16)v.x; z.h[1] = (__bf16)v.y; z.h[2] = (__bf16)v.z; z.h[3] = (__bf16)v.w;
  return z.u;
}

// ---- blocks 0..2047: GN1 stats partials + x->bf16 copy | 2048..2239: W_qkv -> WT bf16 [384][128]
__global__ __launch_bounds__(256) void k_pre(
    const float* __restrict__ x, float* __restrict__ part, unsigned short* __restrict__ xb,
    const float* __restrict__ W, const float* __restrict__ gn1w, unsigned short* __restrict__ WT)
{
  const int t = threadIdx.x;
  if (blockIdx.x >= 2048) {
    int idx = (blockIdx.x - 2048) * 256 + t;   // 49152 total
    int n = idx >> 7, ch = idx & 127;
    WT[idx] = f2bf(gn1w[ch] * W[ch * 384 + n]);
    return;
  }
  const int c = blockIdx.x;                    // 256 blocks/segment, 128 points each
  const float4* xp = (const float4*)x + (size_t)c * 4096;
  ushort4* xo = (ushort4*)xb + (size_t)c * 4096;
  float s = 0.f, q = 0.f;
  #pragma unroll
  for (int i = 0; i < 16; ++i) {
    float4 v = xp[t + i * 256];
    s += v.x + v.y + v.z + v.w;
    q += v.x*v.x + v.y*v.y + v.z*v.z + v.w*v.w;
    xo[t + i * 256] = cvt4(v);
  }
  #pragma unroll
  for (int o = 1; o < 64; o <<= 1) { s += __shfl_xor(s, o); q += __shfl_xor(q, o); }
  __shared__ float red[8];
  int wave = t >> 6, lane = t & 63;
  if (lane == 0) { red[wave*2] = s; red[wave*2+1] = q; }
  __syncthreads();
  if (t == 0) {
    part[c*2]   = red[0] + red[2] + red[4] + red[6];
    part[c*2+1] = red[1] + red[3] + red[5] + red[7];
  }
}

// ---- once per segment: finalize stats1 + fold GN1 bias through all 384 W columns + alpha scales
__global__ __launch_bounds__(384) void k_prep2(
    const float* __restrict__ part, const float* __restrict__ Wqkv,
    const float* __restrict__ gn1w, const float* __restrict__ gn1b,
    float* __restrict__ biasv, float* __restrict__ alpha)
{
  __shared__ float red[8];
  __shared__ float sm[2];
  const int seg = blockIdx.x, t = threadIdx.x;   // 384 threads
  const int wave = t >> 6, lane = t & 63;
  if (t < 256) {
    float s = part[(seg*256 + t)*2], q = part[(seg*256 + t)*2 + 1];
    #pragma unroll
    for (int o = 1; o < 64; o <<= 1) { s += __shfl_xor(s, o); q += __shfl_xor(q, o); }
    if (lane == 0) { red[wave*2] = s; red[wave*2+1] = q; }
  }
  __syncthreads();
  if (t == 0) {
    float s = red[0] + red[2] + red[4] + red[6];
    float q = red[1] + red[3] + red[5] + red[7];
    float mu = s * INVN;
    float var = q * INVN - mu * mu;
    float rs = rsqrtf(var + EPS_GN);
    sm[0] = mu * rs; sm[1] = rs;
  }
  __syncthreads();
  const float mu_rs = sm[0], rs = sm[1];
  float s = 0.f;
  for (int ch = 0; ch < 128; ++ch)
    s += (gn1b[ch] - mu_rs * gn1w[ch]) * Wqkv[ch * 384 + t];
  float scale = (t < 128) ? QSCALE : ((t < 256) ? KSCALE : 1.f);
  biasv[seg*384 + t] = s * scale;
  if (t == 0) {
    alpha[seg*4]   = rs * QSCALE;
    alpha[seg*4+1] = rs * KSCALE;
    alpha[seg*4+2] = rs;
  }
}

// ---- k,v GEMM + exp(k) -> sum_e, ctx += E^T@V. 1024 blocks x 256 thr (4 waves = 4 heads),
//      256 pts/block. No prologue.
__global__ __launch_bounds__(256, 3) void k_kv(
    const unsigned short* __restrict__ xb, const unsigned short* __restrict__ WT,
    const float* __restrict__ biasv, const float* __restrict__ alpha,
    float* __restrict__ sume_p, float* __restrict__ ctx_p)
{
  const int t = threadIdx.x;
  const int h = t >> 6, lane = t & 63;
  const int lm = lane & 15, lg = lane >> 4;
  const int bid = blockIdx.x;               // 1024 = 8 seg * 128 sub
  const int seg = bid >> 7, sub = bid & 127;

  const float alk = alpha[seg*4 + 1], alv = alpha[seg*4 + 2];
  const float ck0 = biasv[seg*384 + 128 + h*32 + lm];
  const float ck1 = biasv[seg*384 + 128 + h*32 + 16 + lm];
  const float cv0 = biasv[seg*384 + 256 + h*32 + lm];
  const float cv1 = biasv[seg*384 + 256 + h*32 + 16 + lm];

  bf16x8 wk[2][4], wv[2][4];
  #pragma unroll
  for (int nt = 0; nt < 2; ++nt)
    #pragma unroll
    for (int kk = 0; kk < 4; ++kk) {
      int row = h*32 + nt*16 + lm;
      wk[nt][kk] = *(const bf16x8*)&WT[(row + 128) * 128 + kk*32 + lg*8];
      wv[nt][kk] = *(const bf16x8*)&WT[(row + 256) * 128 + kk*32 + lg*8];
    }

  f32x4 ctx00 = {0,0,0,0}, ctx01 = {0,0,0,0}, ctx10 = {0,0,0,0}, ctx11 = {0,0,0,0};
  float se0 = 0.f, se1 = 0.f;

  const unsigned short* xw = xb + (size_t)(seg * LSEG + sub*256 + lm) * 128 + lg*8;

#define ISSUE(S, IT) { \
    const unsigned short* p_ = xw + (size_t)((IT) * 16) * 128; \
    S[0] = *(const bf16x8*)(p_);      \
    S[1] = *(const bf16x8*)(p_ + 32); \
    S[2] = *(const bf16x8*)(p_ + 64); \
    S[3] = *(const bf16x8*)(p_ + 96); }

#define COMPUTE(S) { \
    f32x4 ka0 = {0,0,0,0}, ka1 = {0,0,0,0}, va0 = {0,0,0,0}, va1 = {0,0,0,0}; \
    _Pragma("unroll") for (int kk = 0; kk < 4; ++kk) { \
      ka0 = MFMA32(S[kk], wk[0][kk], ka0); \
      ka1 = MFMA32(S[kk], wk[1][kk], ka1); \
    } \
    _Pragma("unroll") for (int kk = 0; kk < 4; ++kk) { \
      va0 = MFMA32(S[kk], wv[0][kk], va0); \
      va1 = MFMA32(S[kk], wv[1][kk], va1); \
    } \
    float e_[8]; \
    _Pragma("unroll") for (int r = 0; r < 4; ++r) { \
      e_[r]     = __expf(fmaf(ka0[r], alk, ck0)); \
      e_[4 + r] = __expf(fmaf(ka1[r], alk, ck1)); \
    } \
    se0 += (e_[0] + e_[1]) + (e_[2] + e_[3]); \
    se1 += (e_[4] + e_[5]) + (e_[6] + e_[7]); \
    s16x4 E0 = pack4(e_[0], e_[1], e_[2], e_[3]); \
    s16x4 E1 = pack4(e_[4], e_[5], e_[6], e_[7]); \
    s16x4 V0 = pack4(fmaf(va0[0], alv, cv0), fmaf(va0[1], alv, cv0), \
                     fmaf(va0[2], alv, cv0), fmaf(va0[3], alv, cv0)); \
    s16x4 V1 = pack4(fmaf(va1[0], alv, cv1), fmaf(va1[1], alv, cv1), \
                     fmaf(va1[2], alv, cv1), fmaf(va1[3], alv, cv1)); \
    ctx00 = MFMA16(E0, V0, ctx00); \
    ctx01 = MFMA16(E0, V1, ctx01); \
    ctx10 = MFMA16(E1, V0, ctx10); \
    ctx11 = MFMA16(E1, V1, ctx11); }

  bf16x8 sA[4], sB[4];
  ISSUE(sA, 0);
  #pragma unroll 1
  for (int it = 0; it < 16; it += 2) {
    ISSUE(sB, it + 1);
    COMPUTE(sA);
    if (it + 2 < 16) ISSUE(sA, it + 2);
    COMPUTE(sB);
  }
#undef ISSUE
#undef COMPUTE

  se0 += __shfl_xor(se0, 16); se0 += __shfl_xor(se0, 32);
  se1 += __shfl_xor(se1, 16); se1 += __shfl_xor(se1, 32);
  if (lane < 16) {
    sume_p[(size_t)bid*128 + h*32 + lm]      = se0;
    sume_p[(size_t)bid*128 + h*32 + 16 + lm] = se1;
  }
  float* cp = ctx_p + (size_t)bid*4096 + h*1024;
  #pragma unroll
  for (int r = 0; r < 4; ++r) {
    cp[(lg*4 + r)*32      + lm]      = ctx00[r];
    cp[(lg*4 + r)*32      + 16 + lm] = ctx01[r];
    cp[(16 + lg*4 + r)*32 + lm]      = ctx10[r];
    cp[(16 + lg*4 + r)*32 + 16 + lm] = ctx11[r];
  }
}

// ---- reduce ctx partials (4-wave split over 128), normalize, fold Wc = blockdiag(ctx)@W_out
__global__ __launch_bounds__(256) void k_wc(
    const float* __restrict__ sume_p, const float* __restrict__ ctx_p,
    const float* __restrict__ Wout, unsigned short* __restrict__ WcT)
{
  __shared__ float sctx4[4][1024];
  __shared__ float sse4[4][32];
  const int t = threadIdx.x, b = blockIdx.x;
  const int w = t >> 6, lane = t & 63;
  const int seg = b >> 5, head = (b >> 3) & 3, ocg = b & 7;

  float acc[16];
  #pragma unroll
  for (int e = 0; e < 16; ++e) acc[e] = 0.f;
  for (int j = w; j < 128; j += 4) {
    const float* cp = ctx_p + (size_t)(seg*128 + j)*4096 + head*1024;
    #pragma unroll
    for (int e = 0; e < 16; ++e) acc[e] += cp[lane + e*64];
  }
  #pragma unroll
  for (int e = 0; e < 16; ++e) sctx4[w][lane + e*64] = acc[e];
  if (lane < 32) {
    float s = 0.f;
    for (int j = w; j < 128; j += 4) s += sume_p[(size_t)(seg*128 + j)*128 + head*32 + lane];
    sse4[w][lane] = s;
  }
  __syncthreads();
  #pragma unroll
  for (int e = 0; e < 4; ++e) {
    int idx = t + e*256;
    sctx4[0][idx] = (sctx4[0][idx] + sctx4[1][idx]) + (sctx4[2][idx] + sctx4[3][idx]);
  }
  __syncthreads();
  #pragma unroll
  for (int e = 0; e < 2; ++e) {
    int idx = t + e*256;              // 512 outputs: 32 kc x 16 oc
    int kc = idx >> 4, ocl = idx & 15;
    int oc = ocg*16 + ocl;
    float s = 0.f;
    #pragma unroll
    for (int vc = 0; vc < 32; ++vc)
      s += sctx4[0][kc*32 + vc] * Wout[(head*32 + vc)*128 + oc];
    float den = (sse4[0][kc] + sse4[1][kc]) + (sse4[2][kc] + sse4[3][kc]);
    WcT[((size_t)seg*128 + oc)*128 + head*32 + kc] = f2bf(s / den);
  }
}

// ---- q recompute -> softmax -> P LDS exchange -> out GEMM -> staged bf16 store + stats2 partials.
//      1024 blocks x 256 thr (4 waves = 4 heads), 256 pts/block. No prologue.
__global__ __launch_bounds__(256, 3) void k_out3(
    const unsigned short* __restrict__ xb, const unsigned short* __restrict__ WT,
    const float* __restrict__ biasv, const float* __restrict__ alpha,
    const unsigned short* __restrict__ WcT,
    float* __restrict__ part2, unsigned short* __restrict__ outm)
{
  __shared__ float red8[8];
  __shared__ __attribute__((aligned(16))) short pbuf[2][8 * 256];               // P exchange, dbuf
  __shared__ __attribute__((aligned(16))) unsigned short sou[2][16 * SOPITCH];  // out staging, dbuf

  const int t = threadIdx.x;
  const int w = t >> 6, lane = t & 63;
  const int lm = lane & 15, lg = lane >> 4;
  const int bid = blockIdx.x;               // 1024 = 8 seg * 128 sub
  const int seg = bid >> 7;
  const size_t cb = (size_t)bid * 256;

  const float alq = alpha[seg*4];
  const float4 cq0 = *(const float4*)&biasv[seg*384 + w*32 + lg*4];
  const float4 cq1 = *(const float4*)&biasv[seg*384 + w*32 + 16 + lg*4];

  bf16x8 wq[2][4];
  #pragma unroll
  for (int nt = 0; nt < 2; ++nt)
    #pragma unroll
    for (int kk = 0; kk < 4; ++kk)
      wq[nt][kk] = *(const bf16x8*)&WT[(w*32 + nt*16 + lm) * 128 + kk*32 + lg*8];
  s16x4 wc[2][8];
  #pragma unroll
  for (int o = 0; o < 2; ++o)
    #pragma unroll
    for (int kt = 0; kt < 8; ++kt)
      wc[o][kt] = *(const s16x4*)&WcT[((size_t)seg*128 + (w*32 + o*16 + lm))*128 + kt*16 + lg*4];

  const unsigned short* xw = xb + (cb + lm) * 128 + lg*8;
  float ssum = 0.f, ssq = 0.f;
  bf16x8 xf0, xf1, xf2, xf3;

#define LOADXF(IT) { \
    const unsigned short* p_ = xw + (size_t)((IT) * 16) * 128; \
    xf0 = *(const bf16x8*)(p_);      \
    xf1 = *(const bf16x8*)(p_ + 32); \
    xf2 = *(const bf16x8*)(p_ + 64); \
    xf3 = *(const bf16x8*)(p_ + 96); }

#define SM2P(D) { \
    f32x4 qa0 = {0,0,0,0}, qa1 = {0,0,0,0}; \
    qa0 = MFMA32(wq[0][0], xf0, qa0); qa1 = MFMA32(wq[1][0], xf0, qa1); \
    qa0 = MFMA32(wq[0][1], xf1, qa0); qa1 = MFMA32(wq[1][1], xf1, qa1); \
    qa0 = MFMA32(wq[0][2], xf2, qa0); qa1 = MFMA32(wq[1][2], xf2, qa1); \
    qa0 = MFMA32(wq[0][3], xf3, qa0); qa1 = MFMA32(wq[1][3], xf3, qa1); \
    float a_[8]; \
    _Pragma("unroll") for (int r = 0; r < 4; ++r) { \
      a_[r]     = fmaf(qa0[r], alq, ((const float*)&cq0)[r]); \
      a_[4 + r] = fmaf(qa1[r], alq, ((const float*)&cq1)[r]); \
    } \
    float m_ = a_[0]; \
    _Pragma("unroll") for (int i = 1; i < 8; ++i) m_ = fmaxf(m_, a_[i]); \
    m_ = fmaxf(m_, __shfl_xor(m_, 16)); \
    m_ = fmaxf(m_, __shfl_xor(m_, 32)); \
    float s_ = 0.f; \
    _Pragma("unroll") for (int i = 0; i < 8; ++i) { a_[i] = __expf(a_[i] - m_); s_ += a_[i]; } \
    s_ += __shfl_xor(s_, 16); \
    s_ += __shfl_xor(s_, 32); \
    float inv_ = 1.f / s_; \
    *(s16x4*)&pbuf[D][(w*2)*256 + lane*4]     = pack4(a_[0]*inv_, a_[1]*inv_, a_[2]*inv_, a_[3]*inv_); \
    *(s16x4*)&pbuf[D][(w*2 + 1)*256 + lane*4] = pack4(a_[4]*inv_, a_[5]*inv_, a_[6]*inv_, a_[7]*inv_); }

  LOADXF(0);
  SM2P(0);

  #pragma unroll 1
  for (int ia = 0; ia < 16; ++ia) {
    const int d = ia & 1;
    __syncthreads();                 // pbuf[d] = P(ia) ready; sou[d^1] = out(ia-1) ready
    if (ia + 1 < 16) LOADXF(ia + 1);
    f32x4 acc0 = {0,0,0,0}, acc1 = {0,0,0,0};
    #pragma unroll
    for (int kt = 0; kt < 8; ++kt) {
      s16x4 pk = *(const s16x4*)&pbuf[d][kt*256 + lane*4];
      acc0 = MFMA16(wc[0][kt], pk, acc0);
      acc1 = MFMA16(wc[1][kt], pk, acc1);
    }
    if (ia > 0) {
      #pragma unroll
      for (int j = 0; j < 2; ++j) {
        int f = t + j*256;
        int pt = f >> 5, cc = f & 31;
        ((ushort4*)outm)[(cb + (size_t)(ia-1)*16 + pt)*32 + cc] =
            *(const ushort4*)&sou[d^1][pt*SOPITCH + cc*4];
      }
    }
    #pragma unroll
    for (int r = 0; r < 4; ++r) {
      ssum += acc0[r] + acc1[r];
      ssq  += acc0[r]*acc0[r] + acc1[r]*acc1[r];
    }
    {
      unsigned short* dst = &sou[d][lm*SOPITCH + w*32 + lg*4];
      dst[0] = f2bf(acc0[0]); dst[1] = f2bf(acc0[1]);
      dst[2] = f2bf(acc0[2]); dst[3] = f2bf(acc0[3]);
      dst += 16;
      dst[0] = f2bf(acc1[0]); dst[1] = f2bf(acc1[1]);
      dst[2] = f2bf(acc1[2]); dst[3] = f2bf(acc1[3]);
    }
    if (ia + 1 < 16) SM2P(d ^ 1);
  }
  __syncthreads();
  #pragma unroll
  for (int j = 0; j < 2; ++j) {
    int f = t + j*256;
    int pt = f >> 5, cc = f & 31;
    ((ushort4*)outm)[(cb + (size_t)15*16 + pt)*32 + cc] =
        *(const ushort4*)&sou[1][pt*SOPITCH + cc*4];
  }
#undef LOADXF
#undef SM2P

  #pragma unroll
  for (int o = 1; o < 64; o <<= 1) { ssum += __shfl_xor(ssum, o); ssq += __shfl_xor(ssq, o); }
  if (lane == 0) { red8[w*2] = ssum; red8[w*2+1] = ssq; }
  __syncthreads();
  if (t == 0) {
    part2[bid*2]   = red8[0] + red8[2] + red8[4] + red8[6];
    part2[bid*2+1] = red8[1] + red8[3] + red8[5] + red8[7];
  }
}

// ---- GN2 (stats from part2: 128 partials/seg) + residual
__global__ __launch_bounds__(256) void k_fin(
    const unsigned short* __restrict__ xb, const unsigned short* __restrict__ out_ws,
    const float* __restrict__ part2, const float* __restrict__ gn2w, const float* __restrict__ gn2b,
    float* __restrict__ y)
{
  __shared__ float sm[2];
  __shared__ float red[4];
  const int t = threadIdx.x;
  const int b = blockIdx.x >> 8, blk = blockIdx.x & 255;
  if (t < 128) {
    float s = part2[(b*128 + t)*2], q = part2[(b*128 + t)*2 + 1];
    #pragma unroll
    for (int o = 1; o < 64; o <<= 1) { s += __shfl_xor(s, o); q += __shfl_xor(q, o); }
    if ((t & 63) == 0) { red[(t>>6)*2] = s; red[(t>>6)*2+1] = q; }
  }
  __syncthreads();
  if (t == 0) {
    float ss = red[0] + red[2];
    float qq = red[1] + red[3];
    float mu = ss * INVN;
    float var = qq * INVN - mu * mu;
    sm[0] = mu; sm[1] = rsqrtf(var + EPS_GN);
  }
  __syncthreads();
  const float mu = sm[0], rs = sm[1];
  const int c4 = t & 31;
  const float4 w4 = *(const float4*)&gn2w[c4*4];
  const float4 g4 = *(const float4*)&gn2b[c4*4];
  const size_t base = (size_t)b * 1048576 + (size_t)blk * 4096;
  const ushort4* xp = (const ushort4*)xb + base;
  const ushort4* op = (const ushort4*)out_ws + base;
  float4* yp = (float4*)y + base;
  #pragma unroll
  for (int i = 0; i < 16; ++i) {
    int f = t + i * 256;
    ushort4 xv = xp[f];
    ushort4 ov = op[f];
    float4 r;
    r.x = (bf2f(ov.x) - mu) * rs * w4.x + g4.x + bf2f(xv.x);
    r.y = (bf2f(ov.y) - mu) * rs * w4.y + g4.y + bf2f(xv.y);
    r.z = (bf2f(ov.z) - mu) * rs * w4.z + g4.z + bf2f(xv.z);
    r.w = (bf2f(ov.w) - mu) * rs * w4.w + g4.w + bf2f(xv.w);
    yp[f] = r;
  }
}

extern "C" void kernel_launch(void* const* d_in, const int* in_sizes, int n_in,
                              void* d_out, int out_size, void* d_ws, size_t ws_size,
                              hipStream_t stream) {
  const float* x    = (const float*)d_in[0];
  const float* gn1w = (const float*)d_in[1];
  const float* gn1b = (const float*)d_in[2];
  const float* Wqkv = (const float*)d_in[3];
  const float* Wout = (const float*)d_in[4];
  const float* gn2w = (const float*)d_in[5];
  const float* gn2b = (const float*)d_in[6];
  float* y = (float*)d_out;
  char* ws = (char*)d_ws;

  float*          part   = (float*)(ws + 0);                 // 2048*2 f32 = 16384
  float*          part2  = (float*)(ws + 16384);             // 1024*2 f32 = 8192
  unsigned short* WT     = (unsigned short*)(ws + 24576);    // 384*128 bf16 = 98304
  unsigned short* WcT    = (unsigned short*)(ws + 122880);   // 8*128*128 bf16 = 262144
  float*          biasv  = (float*)(ws + 385024);            // 8*384 f32 = 12288
  float*          alphav = (float*)(ws + 397312);            // 8*4 f32
  float*          sume_p = (float*)(ws + 401408);            // 1024*128 f32 = 524288
  float*          ctx_p  = (float*)(ws + 925696);            // 1024*4096 f32 = 16777216
  unsigned short* xb     = (unsigned short*)(ws + 17702912); // 67108864
  unsigned short* outm   = (unsigned short*)(ws + 84811776); // 67108864

  hipLaunchKernelGGL(k_pre,   dim3(2240), dim3(256), 0, stream, x, part, xb, Wqkv, gn1w, WT);
  hipLaunchKernelGGL(k_prep2, dim3(8),    dim3(384), 0, stream, part, Wqkv, gn1w, gn1b, biasv, alphav);
  hipLaunchKernelGGL(k_kv,    dim3(1024), dim3(256), 0, stream, xb, WT, biasv, alphav, sume_p, ctx_p);
  hipLaunchKernelGGL(k_wc,    dim3(256),  dim3(256), 0, stream, sume_p, ctx_p, Wout, WcT);
  hipLaunchKernelGGL(k_out3,  dim3(1024), dim3(256), 0, stream, xb, WT, biasv, alphav, WcT, part2, outm);
  hipLaunchKernelGGL(k_fin,   dim3(2048), dim3(256), 0, stream, xb, outm, part2, gn2w, gn2b, y);
}

// Round 12
// 193.807 us; speedup vs baseline: 2.6211x; 1.1519x over previous
//
#include <hip/hip_runtime.h>

#define NSEG 8
#define LSEG 32768
#define EPS_GN 1e-5f
#define KSCALE 0.005524271728019903f   // 1/sqrt(32768)
#define QSCALE 0.17677669529663687f    // 1/sqrt(32)
#define INVN 2.384185791015625e-07f    // 1/4194304
#define SOPITCH 260                     // sou pitch in shorts

typedef __attribute__((ext_vector_type(4))) float f32x4;
typedef __attribute__((ext_vector_type(8))) __bf16 bf16x8;
typedef __attribute__((ext_vector_type(4))) short s16x4;

#define MFMA32(A, B, C) __builtin_amdgcn_mfma_f32_16x16x32_bf16(A, B, C, 0, 0, 0)
#define MFMA16(A, B, C) __builtin_amdgcn_mfma_f32_16x16x16bf16_1k(A, B, C, 0, 0, 0)

static __device__ __forceinline__ unsigned short f2bf(float f) {
  unsigned int u = __float_as_uint(f);
  u += 0x7fffu + ((u >> 16) & 1u);
  return (unsigned short)(u >> 16);
}
static __device__ __forceinline__ float bf2f(unsigned short s) {
  return __uint_as_float(((unsigned int)s) << 16);
}
static __device__ __forceinline__ s16x4 pack4(float a, float b, float c, float d) {
  union { __bf16 h[4]; s16x4 s; } u;
  u.h[0] = (__bf16)a; u.h[1] = (__bf16)b; u.h[2] = (__bf16)c; u.h[3] = (__bf16)d;
  return u.s;
}
static __device__ __forceinline__ ushort4 cvt4(float4 v) {
  union { __bf16 h[4]; ushort4 u; } z;
  z.h[0] = (__bf16)v.x; z.h[1] = (__bf16)v.y; z.h[2] = (__bf16)v.z; z.h[3] = (__bf16)v.w;
  return z.u;
}

// ---- blocks 0..2047: GN1 stats partials + x->bf16 copy | 2048..2239: W_qkv -> WT bf16 [384][128]
__global__ __launch_bounds__(256) void k_pre(
    const float* __restrict__ x, float* __restrict__ part, unsigned short* __restrict__ xb,
    const float* __restrict__ W, const float* __restrict__ gn1w, unsigned short* __restrict__ WT)
{
  const int t = threadIdx.x;
  if (blockIdx.x >= 2048) {
    int idx = (blockIdx.x - 2048) * 256 + t;   // 49152 total
    int n = idx >> 7, ch = idx & 127;
    WT[idx] = f2bf(gn1w[ch] * W[ch * 384 + n]);
    return;
  }
  const int c = blockIdx.x;                    // 256 blocks/segment, 128 points each
  const float4* xp = (const float4*)x + (size_t)c * 4096;
  ushort4* xo = (ushort4*)xb + (size_t)c * 4096;
  float s = 0.f, q = 0.f;
  #pragma unroll
  for (int i = 0; i < 16; ++i) {
    float4 v = xp[t + i * 256];
    s += v.x + v.y + v.z + v.w;
    q += v.x*v.x + v.y*v.y + v.z*v.z + v.w*v.w;
    xo[t + i * 256] = cvt4(v);
  }
  #pragma unroll
  for (int o = 1; o < 64; o <<= 1) { s += __shfl_xor(s, o); q += __shfl_xor(q, o); }
  __shared__ float red[8];
  int wave = t >> 6, lane = t & 63;
  if (lane == 0) { red[wave*2] = s; red[wave*2+1] = q; }
  __syncthreads();
  if (t == 0) {
    part[c*2]   = red[0] + red[2] + red[4] + red[6];
    part[c*2+1] = red[1] + red[3] + red[5] + red[7];
  }
}

// ---- once per segment: finalize stats1 + fold GN1 bias through all 384 W columns + alpha scales
__global__ __launch_bounds__(384) void k_prep2(
    const float* __restrict__ part, const float* __restrict__ Wqkv,
    const float* __restrict__ gn1w, const float* __restrict__ gn1b,
    float* __restrict__ biasv, float* __restrict__ alpha)
{
  __shared__ float red[8];
  __shared__ float sm[2];
  const int seg = blockIdx.x, t = threadIdx.x;   // 384 threads
  const int wave = t >> 6, lane = t & 63;
  if (t < 256) {
    float s = part[(seg*256 + t)*2], q = part[(seg*256 + t)*2 + 1];
    #pragma unroll
    for (int o = 1; o < 64; o <<= 1) { s += __shfl_xor(s, o); q += __shfl_xor(q, o); }
    if (lane == 0) { red[wave*2] = s; red[wave*2+1] = q; }
  }
  __syncthreads();
  if (t == 0) {
    float s = red[0] + red[2] + red[4] + red[6];
    float q = red[1] + red[3] + red[5] + red[7];
    float mu = s * INVN;
    float var = q * INVN - mu * mu;
    float rs = rsqrtf(var + EPS_GN);
    sm[0] = mu * rs; sm[1] = rs;
  }
  __syncthreads();
  const float mu_rs = sm[0], rs = sm[1];
  float s = 0.f;
  for (int ch = 0; ch < 128; ++ch)
    s += (gn1b[ch] - mu_rs * gn1w[ch]) * Wqkv[ch * 384 + t];
  float scale = (t < 128) ? QSCALE : ((t < 256) ? KSCALE : 1.f);
  biasv[seg*384 + t] = s * scale;
  if (t == 0) {
    alpha[seg*4]   = rs * QSCALE;
    alpha[seg*4+1] = rs * KSCALE;
    alpha[seg*4+2] = rs;
  }
}

// ---- k,v GEMM + exp(k) -> sum_e, ctx += E^T@V. 512 blocks x 256 thr (4 waves = 4 heads).
//      4-deep load pipeline, no prologue.
__global__ __launch_bounds__(256, 2) void k_kv(
    const unsigned short* __restrict__ xb, const unsigned short* __restrict__ WT,
    const float* __restrict__ biasv, const float* __restrict__ alpha,
    float* __restrict__ sume_p, float* __restrict__ ctx_p)
{
  const int t = threadIdx.x;
  const int h = t >> 6, lane = t & 63;
  const int lm = lane & 15, lg = lane >> 4;
  const int bid = blockIdx.x;               // 512 = 8 seg * 64 sub
  const int seg = bid >> 6, sub = bid & 63;

  const float alk = alpha[seg*4 + 1], alv = alpha[seg*4 + 2];
  const float ck0 = biasv[seg*384 + 128 + h*32 + lm];
  const float ck1 = biasv[seg*384 + 128 + h*32 + 16 + lm];
  const float cv0 = biasv[seg*384 + 256 + h*32 + lm];
  const float cv1 = biasv[seg*384 + 256 + h*32 + 16 + lm];

  bf16x8 wk[2][4], wv[2][4];
  #pragma unroll
  for (int nt = 0; nt < 2; ++nt)
    #pragma unroll
    for (int kk = 0; kk < 4; ++kk) {
      int row = h*32 + nt*16 + lm;
      wk[nt][kk] = *(const bf16x8*)&WT[(row + 128) * 128 + kk*32 + lg*8];
      wv[nt][kk] = *(const bf16x8*)&WT[(row + 256) * 128 + kk*32 + lg*8];
    }

  f32x4 ctx00 = {0,0,0,0}, ctx01 = {0,0,0,0}, ctx10 = {0,0,0,0}, ctx11 = {0,0,0,0};
  float se0 = 0.f, se1 = 0.f;

  const unsigned short* xw = xb + (size_t)(seg * LSEG + sub*512 + lm) * 128 + lg*8;

#define ISSUE(S, IT) { \
    const unsigned short* p_ = xw + (size_t)((IT) * 16) * 128; \
    S[0] = *(const bf16x8*)(p_);      \
    S[1] = *(const bf16x8*)(p_ + 32); \
    S[2] = *(const bf16x8*)(p_ + 64); \
    S[3] = *(const bf16x8*)(p_ + 96); }

#define COMPUTE(S) { \
    f32x4 ka0 = {0,0,0,0}, ka1 = {0,0,0,0}, va0 = {0,0,0,0}, va1 = {0,0,0,0}; \
    _Pragma("unroll") for (int kk = 0; kk < 4; ++kk) { \
      ka0 = MFMA32(S[kk], wk[0][kk], ka0); \
      ka1 = MFMA32(S[kk], wk[1][kk], ka1); \
    } \
    _Pragma("unroll") for (int kk = 0; kk < 4; ++kk) { \
      va0 = MFMA32(S[kk], wv[0][kk], va0); \
      va1 = MFMA32(S[kk], wv[1][kk], va1); \
    } \
    float e_[8]; \
    _Pragma("unroll") for (int r = 0; r < 4; ++r) { \
      e_[r]     = __expf(fmaf(ka0[r], alk, ck0)); \
      e_[4 + r] = __expf(fmaf(ka1[r], alk, ck1)); \
    } \
    se0 += (e_[0] + e_[1]) + (e_[2] + e_[3]); \
    se1 += (e_[4] + e_[5]) + (e_[6] + e_[7]); \
    s16x4 E0 = pack4(e_[0], e_[1], e_[2], e_[3]); \
    s16x4 E1 = pack4(e_[4], e_[5], e_[6], e_[7]); \
    s16x4 V0 = pack4(fmaf(va0[0], alv, cv0), fmaf(va0[1], alv, cv0), \
                     fmaf(va0[2], alv, cv0), fmaf(va0[3], alv, cv0)); \
    s16x4 V1 = pack4(fmaf(va1[0], alv, cv1), fmaf(va1[1], alv, cv1), \
                     fmaf(va1[2], alv, cv1), fmaf(va1[3], alv, cv1)); \
    ctx00 = MFMA16(E0, V0, ctx00); \
    ctx01 = MFMA16(E0, V1, ctx01); \
    ctx10 = MFMA16(E1, V0, ctx10); \
    ctx11 = MFMA16(E1, V1, ctx11); }

  bf16x8 sA[4], sB[4], sC[4], sD[4];
  ISSUE(sA, 0);
  ISSUE(sB, 1);
  #pragma unroll 1
  for (int it = 0; it < 32; it += 4) {
    ISSUE(sC, it + 2);
    COMPUTE(sA);
    ISSUE(sD, it + 3);
    COMPUTE(sB);
    if (it + 4 < 32) ISSUE(sA, it + 4);
    COMPUTE(sC);
    if (it + 5 < 32) ISSUE(sB, it + 5);
    COMPUTE(sD);
  }
#undef ISSUE
#undef COMPUTE

  se0 += __shfl_xor(se0, 16); se0 += __shfl_xor(se0, 32);
  se1 += __shfl_xor(se1, 16); se1 += __shfl_xor(se1, 32);
  if (lane < 16) {
    sume_p[(size_t)bid*128 + h*32 + lm]      = se0;
    sume_p[(size_t)bid*128 + h*32 + 16 + lm] = se1;
  }
  float* cp = ctx_p + (size_t)bid*4096 + h*1024;
  #pragma unroll
  for (int r = 0; r < 4; ++r) {
    cp[(lg*4 + r)*32      + lm]      = ctx00[r];
    cp[(lg*4 + r)*32      + 16 + lm] = ctx01[r];
    cp[(16 + lg*4 + r)*32 + lm]      = ctx10[r];
    cp[(16 + lg*4 + r)*32 + 16 + lm] = ctx11[r];
  }
}

// ---- reduce ctx partials, normalize, fold Wc = blockdiag(ctx)@W_out -> WcT[seg][oc][qc] bf16
__global__ __launch_bounds__(256) void k_wc(
    const float* __restrict__ sume_p, const float* __restrict__ ctx_p,
    const float* __restrict__ Wout, unsigned short* __restrict__ WcT)
{
  __shared__ float sctx[1024];
  __shared__ float sse[32];
  const int t = threadIdx.x, b = blockIdx.x;
  const int seg = b >> 5, head = (b >> 3) & 3, ocg = b & 7;
  float acc[4] = {0.f, 0.f, 0.f, 0.f};
  for (int j = 0; j < 64; ++j) {
    const float* cp = ctx_p + (size_t)(seg*64 + j)*4096 + head*1024;
    #pragma unroll
    for (int e = 0; e < 4; ++e) acc[e] += cp[t + e*256];
  }
  if (t < 32) {
    float s = 0.f;
    for (int j = 0; j < 64; ++j) s += sume_p[(size_t)(seg*64 + j)*128 + head*32 + t];
    sse[t] = s;
  }
  #pragma unroll
  for (int e = 0; e < 4; ++e) sctx[t + e*256] = acc[e];
  __syncthreads();
  #pragma unroll
  for (int e = 0; e < 2; ++e) {
    int idx = t + e*256;              // 512 outputs: 32 kc x 16 oc
    int kc = idx >> 4, ocl = idx & 15;
    int oc = ocg*16 + ocl;
    float s = 0.f;
    #pragma unroll
    for (int vc = 0; vc < 32; ++vc)
      s += sctx[kc*32 + vc] * Wout[(head*32 + vc)*128 + oc];
    WcT[((size_t)seg*128 + oc)*128 + head*32 + kc] = f2bf(s / sse[kc]);
  }
}

// ---- q recompute -> softmax -> P LDS exchange -> out GEMM -> staged bf16 store + stats2 partials.
//      512 blocks x 256 thr (4 waves = 4 heads), 512 pts each. Loads issued one full phase ahead.
__global__ __launch_bounds__(256, 2) void k_out3(
    const unsigned short* __restrict__ xb, const unsigned short* __restrict__ WT,
    const float* __restrict__ biasv, const float* __restrict__ alpha,
    const unsigned short* __restrict__ WcT,
    float* __restrict__ part2, unsigned short* __restrict__ outm)
{
  __shared__ float red8[8];
  __shared__ __attribute__((aligned(16))) short pbuf[2][8 * 256];               // P exchange, dbuf
  __shared__ __attribute__((aligned(16))) unsigned short sou[2][16 * SOPITCH];  // out staging, dbuf

  const int t = threadIdx.x;
  const int w = t >> 6, lane = t & 63;
  const int lm = lane & 15, lg = lane >> 4;
  const int bid = blockIdx.x;               // 512 = 8 seg * 64 sub
  const int seg = bid >> 6;
  const size_t cb = (size_t)bid * 512;

  const float alq = alpha[seg*4];
  const float4 cq0 = *(const float4*)&biasv[seg*384 + w*32 + lg*4];
  const float4 cq1 = *(const float4*)&biasv[seg*384 + w*32 + 16 + lg*4];

  bf16x8 wq[2][4];
  #pragma unroll
  for (int nt = 0; nt < 2; ++nt)
    #pragma unroll
    for (int kk = 0; kk < 4; ++kk)
      wq[nt][kk] = *(const bf16x8*)&WT[(w*32 + nt*16 + lm) * 128 + kk*32 + lg*8];
  s16x4 wc[2][8];
  #pragma unroll
  for (int o = 0; o < 2; ++o)
    #pragma unroll
    for (int kt = 0; kt < 8; ++kt)
      wc[o][kt] = *(const s16x4*)&WcT[((size_t)seg*128 + (w*32 + o*16 + lm))*128 + kt*16 + lg*4];

  const unsigned short* xw = xb + (cb + lm) * 128 + lg*8;
  float ssum = 0.f, ssq = 0.f;
  bf16x8 xa0, xa1, xa2, xa3;   // phase-A prefetch set
  bf16x8 xb0, xb1, xb2, xb3;   // phase-B prefetch set

#define LOADA(IT) { \
    const unsigned short* p_ = xw + (size_t)((IT) * 16) * 128; \
    xa0 = *(const bf16x8*)(p_);      \
    xa1 = *(const bf16x8*)(p_ + 32); \
    xa2 = *(const bf16x8*)(p_ + 64); \
    xa3 = *(const bf16x8*)(p_ + 96); }

#define LOADB(IT) { \
    const unsigned short* p_ = xw + (size_t)((IT) * 16) * 128; \
    xb0 = *(const bf16x8*)(p_);      \
    xb1 = *(const bf16x8*)(p_ + 32); \
    xb2 = *(const bf16x8*)(p_ + 64); \
    xb3 = *(const bf16x8*)(p_ + 96); }

#define SM2P_X(D, X0, X1, X2, X3) { \
    f32x4 qa0 = {0,0,0,0}, qa1 = {0,0,0,0}; \
    qa0 = MFMA32(wq[0][0], X0, qa0); qa1 = MFMA32(wq[1][0], X0, qa1); \
    qa0 = MFMA32(wq[0][1], X1, qa0); qa1 = MFMA32(wq[1][1], X1, qa1); \
    qa0 = MFMA32(wq[0][2], X2, qa0); qa1 = MFMA32(wq[1][2], X2, qa1); \
    qa0 = MFMA32(wq[0][3], X3, qa0); qa1 = MFMA32(wq[1][3], X3, qa1); \
    float a_[8]; \
    _Pragma("unroll") for (int r = 0; r < 4; ++r) { \
      a_[r]     = fmaf(qa0[r], alq, ((const float*)&cq0)[r]); \
      a_[4 + r] = fmaf(qa1[r], alq, ((const float*)&cq1)[r]); \
    } \
    float m_ = a_[0]; \
    _Pragma("unroll") for (int i = 1; i < 8; ++i) m_ = fmaxf(m_, a_[i]); \
    m_ = fmaxf(m_, __shfl_xor(m_, 16)); \
    m_ = fmaxf(m_, __shfl_xor(m_, 32)); \
    float s_ = 0.f; \
    _Pragma("unroll") for (int i = 0; i < 8; ++i) { a_[i] = __expf(a_[i] - m_); s_ += a_[i]; } \
    s_ += __shfl_xor(s_, 16); \
    s_ += __shfl_xor(s_, 32); \
    float inv_ = 1.f / s_; \
    *(s16x4*)&pbuf[D][(w*2)*256 + lane*4]     = pack4(a_[0]*inv_, a_[1]*inv_, a_[2]*inv_, a_[3]*inv_); \
    *(s16x4*)&pbuf[D][(w*2 + 1)*256 + lane*4] = pack4(a_[4]*inv_, a_[5]*inv_, a_[6]*inv_, a_[7]*inv_); }

#define GEMMSTORE(D, IA) { \
    f32x4 acc0 = {0,0,0,0}, acc1 = {0,0,0,0}; \
    _Pragma("unroll") \
    for (int kt = 0; kt < 8; ++kt) { \
      s16x4 pk = *(const s16x4*)&pbuf[D][kt*256 + lane*4]; \
      acc0 = MFMA16(wc[0][kt], pk, acc0); \
      acc1 = MFMA16(wc[1][kt], pk, acc1); \
    } \
    if ((IA) > 0) { \
      _Pragma("unroll") \
      for (int j = 0; j < 2; ++j) { \
        int f = t + j*256; \
        int pt = f >> 5, cc = f & 31; \
        ((ushort4*)outm)[(cb + (size_t)((IA)-1)*16 + pt)*32 + cc] = \
            *(const ushort4*)&sou[(D)^1][pt*SOPITCH + cc*4]; \
      } \
    } \
    _Pragma("unroll") \
    for (int r = 0; r < 4; ++r) { \
      ssum += acc0[r] + acc1[r]; \
      ssq  += acc0[r]*acc0[r] + acc1[r]*acc1[r]; \
    } \
    { \
      unsigned short* dst = &sou[D][lm*SOPITCH + w*32 + lg*4]; \
      dst[0] = f2bf(acc0[0]); dst[1] = f2bf(acc0[1]); \
      dst[2] = f2bf(acc0[2]); dst[3] = f2bf(acc0[3]); \
      dst += 16; \
      dst[0] = f2bf(acc1[0]); dst[1] = f2bf(acc1[1]); \
      dst[2] = f2bf(acc1[2]); dst[3] = f2bf(acc1[3]); \
    } }

  LOADA(0);
  SM2P_X(0, xa0, xa1, xa2, xa3);      // P(0) -> pbuf[0] (only prologue stall)
  LOADB(1);                           // tile 1 in flight across phase 0

  #pragma unroll 1
  for (int ia = 0; ia < 32; ia += 2) {
    __syncthreads();                  // pbuf[0]=P(ia) ready; sou[1]=out(ia-1) ready
    if (ia + 2 < 32) LOADA(ia + 2);   // in flight across this whole phase
    GEMMSTORE(0, ia);                 // GEMM tile ia; store tile ia-1; stage sou[0]=out(ia)
    SM2P_X(1, xb0, xb1, xb2, xb3);    // P(ia+1): loads issued one full phase ago
    __syncthreads();                  // pbuf[1]=P(ia+1) ready; sou[0]=out(ia) ready
    if (ia + 3 < 32) LOADB(ia + 3);
    GEMMSTORE(1, ia + 1);             // GEMM tile ia+1; store tile ia; stage sou[1]=out(ia+1)
    if (ia + 2 < 32) SM2P_X(0, xa0, xa1, xa2, xa3);  // P(ia+2)
  }
  __syncthreads();
  // tail: store tile 31 (in sou[1])
  #pragma unroll
  for (int j = 0; j < 2; ++j) {
    int f = t + j*256;
    int pt = f >> 5, cc = f & 31;
    ((ushort4*)outm)[(cb + (size_t)31*16 + pt)*32 + cc] =
        *(const ushort4*)&sou[1][pt*SOPITCH + cc*4];
  }
#undef LOADA
#undef LOADB
#undef SM2P_X
#undef GEMMSTORE

  #pragma unroll
  for (int o = 1; o < 64; o <<= 1) { ssum += __shfl_xor(ssum, o); ssq += __shfl_xor(ssq, o); }
  if (lane == 0) { red8[w*2] = ssum; red8[w*2+1] = ssq; }
  __syncthreads();
  if (t == 0) {
    part2[bid*2]   = red8[0] + red8[2] + red8[4] + red8[6];
    part2[bid*2+1] = red8[1] + red8[3] + red8[5] + red8[7];
  }
}

// ---- GN2 (stats from part2: 64 partials/seg) + residual
__global__ __launch_bounds__(256) void k_fin(
    const unsigned short* __restrict__ xb, const unsigned short* __restrict__ out_ws,
    const float* __restrict__ part2, const float* __restrict__ gn2w, const float* __restrict__ gn2b,
    float* __restrict__ y)
{
  __shared__ float sm[2];
  const int t = threadIdx.x;
  const int b = blockIdx.x >> 8, blk = blockIdx.x & 255;
  if (t < 64) {
    float s = part2[(b*64 + t)*2], q = part2[(b*64 + t)*2 + 1];
    #pragma unroll
    for (int o = 1; o < 64; o <<= 1) { s += __shfl_xor(s, o); q += __shfl_xor(q, o); }
    if (t == 0) {
      float mu = s * INVN;
      float var = q * INVN - mu * mu;
      sm[0] = mu; sm[1] = rsqrtf(var + EPS_GN);
    }
  }
  __syncthreads();
  const float mu = sm[0], rs = sm[1];
  const int c4 = t & 31;
  const float4 w4 = *(const float4*)&gn2w[c4*4];
  const float4 g4 = *(const float4*)&gn2b[c4*4];
  const size_t base = (size_t)b * 1048576 + (size_t)blk * 4096;
  const ushort4* xp = (const ushort4*)xb + base;
  const ushort4* op = (const ushort4*)out_ws + base;
  float4* yp = (float4*)y + base;
  #pragma unroll
  for (int i = 0; i < 16; ++i) {
    int f = t + i * 256;
    ushort4 xv = xp[f];
    ushort4 ov = op[f];
    float4 r;
    r.x = (bf2f(ov.x) - mu) * rs * w4.x + g4.x + bf2f(xv.x);
    r.y = (bf2f(ov.y) - mu) * rs * w4.y + g4.y + bf2f(xv.y);
    r.z = (bf2f(ov.z) - mu) * rs * w4.z + g4.z + bf2f(xv.z);
    r.w = (bf2f(ov.w) - mu) * rs * w4.w + g4.w + bf2f(xv.w);
    yp[f] = r;
  }
}

extern "C" void kernel_launch(void* const* d_in, const int* in_sizes, int n_in,
                              void* d_out, int out_size, void* d_ws, size_t ws_size,
                              hipStream_t stream) {
  const float* x    = (const float*)d_in[0];
  const float* gn1w = (const float*)d_in[1];
  const float* gn1b = (const float*)d_in[2];
  const float* Wqkv = (const float*)d_in[3];
  const float* Wout = (const float*)d_in[4];
  const float* gn2w = (const float*)d_in[5];
  const float* gn2b = (const float*)d_in[6];
  float* y = (float*)d_out;
  char* ws = (char*)d_ws;

  float*          part   = (float*)(ws + 0);                 // 2048*2 f32 = 16384
  float*          part2  = (float*)(ws + 16384);             // 512*2 f32 = 4096
  unsigned short* WT     = (unsigned short*)(ws + 24576);    // 384*128 bf16 = 98304
  unsigned short* WcT    = (unsigned short*)(ws + 122880);   // 8*128*128 bf16 = 262144
  float*          biasv  = (float*)(ws + 385024);            // 8*384 f32 = 12288
  float*          alphav = (float*)(ws + 397312);            // 8*4 f32
  float*          sume_p = (float*)(ws + 401408);            // 512*128 f32 = 262144
  float*          ctx_p  = (float*)(ws + 663552);            // 512*4096 f32 = 8388608
  unsigned short* xb     = (unsigned short*)(ws + 9052160);  // 67108864
  unsigned short* outm   = (unsigned short*)(ws + 76161024); // 67108864

  hipLaunchKernelGGL(k_pre,   dim3(2240), dim3(256), 0, stream, x, part, xb, Wqkv, gn1w, WT);
  hipLaunchKernelGGL(k_prep2, dim3(8),    dim3(384), 0, stream, part, Wqkv, gn1w, gn1b, biasv, alphav);
  hipLaunchKernelGGL(k_kv,    dim3(512),  dim3(256), 0, stream, xb, WT, biasv, alphav, sume_p, ctx_p);
  hipLaunchKernelGGL(k_wc,    dim3(256),  dim3(256), 0, stream, sume_p, ctx_p, Wout, WcT);
  hipLaunchKernelGGL(k_out3,  dim3(512),  dim3(256), 0, stream, xb, WT, biasv, alphav, WcT, part2, outm);
  hipLaunchKernelGGL(k_fin,   dim3(2048), dim3(256), 0, stream, xb, outm, part2, gn2w, gn2b, y);
}

// Round 14
// 191.675 us; speedup vs baseline: 2.6503x; 1.0111x over previous
//
#include <hip/hip_runtime.h>

#define NSEG 8
#define LSEG 32768
#define EPS_GN 1e-5f
#define KSCALE 0.005524271728019903f   // 1/sqrt(32768)
#define QSCALE 0.17677669529663687f    // 1/sqrt(32)
#define INVN 2.384185791015625e-07f    // 1/4194304
#define SOPITCH 264                     // sou pitch in shorts: 528B rows -> 16B-aligned, <=2-way banks

typedef __attribute__((ext_vector_type(4))) float f32x4;
typedef __attribute__((ext_vector_type(8))) __bf16 bf16x8;
typedef __attribute__((ext_vector_type(4))) short s16x4;

#define MFMA32(A, B, C) __builtin_amdgcn_mfma_f32_16x16x32_bf16(A, B, C, 0, 0, 0)
#define MFMA16(A, B, C) __builtin_amdgcn_mfma_f32_16x16x16bf16_1k(A, B, C, 0, 0, 0)

static __device__ __forceinline__ unsigned short f2bf(float f) {
  unsigned int u = __float_as_uint(f);
  u += 0x7fffu + ((u >> 16) & 1u);
  return (unsigned short)(u >> 16);
}
static __device__ __forceinline__ float bf2f(unsigned short s) {
  return __uint_as_float(((unsigned int)s) << 16);
}
static __device__ __forceinline__ s16x4 pack4(float a, float b, float c, float d) {
  union { __bf16 h[4]; s16x4 s; } u;
  u.h[0] = (__bf16)a; u.h[1] = (__bf16)b; u.h[2] = (__bf16)c; u.h[3] = (__bf16)d;
  return u.s;
}
static __device__ __forceinline__ uint4 cvt8(float4 v0, float4 v1) {
  union { __bf16 h[8]; uint4 u; } z;
  z.h[0] = (__bf16)v0.x; z.h[1] = (__bf16)v0.y; z.h[2] = (__bf16)v0.z; z.h[3] = (__bf16)v0.w;
  z.h[4] = (__bf16)v1.x; z.h[5] = (__bf16)v1.y; z.h[6] = (__bf16)v1.z; z.h[7] = (__bf16)v1.w;
  return z.u;
}

// ---- blocks 0..2047: GN1 stats partials + x->bf16 copy | 2048..2239: W_qkv -> WT bf16 [384][128]
__global__ __launch_bounds__(256) void k_pre(
    const float* __restrict__ x, float* __restrict__ part, unsigned short* __restrict__ xb,
    const float* __restrict__ W, const float* __restrict__ gn1w, unsigned short* __restrict__ WT)
{
  const int t = threadIdx.x;
  if (blockIdx.x >= 2048) {
    int idx = (blockIdx.x - 2048) * 256 + t;   // 49152 total
    int n = idx >> 7, ch = idx & 127;
    WT[idx] = f2bf(gn1w[ch] * W[ch * 384 + n]);
    return;
  }
  const int c = blockIdx.x;                    // 256 blocks/segment, 128 points each
  const float4* xp = (const float4*)x + (size_t)c * 4096;
  ushort4* xo = (ushort4*)xb + (size_t)c * 4096;
  float s = 0.f, q = 0.f;
  #pragma unroll
  for (int k = 0; k < 8; ++k) {
    int f = 2*t + 512*k;
    float4 v0 = xp[f];
    float4 v1 = xp[f + 1];
    s += (v0.x + v0.y + v0.z + v0.w) + (v1.x + v1.y + v1.z + v1.w);
    q += (v0.x*v0.x + v0.y*v0.y + v0.z*v0.z + v0.w*v0.w)
       + (v1.x*v1.x + v1.y*v1.y + v1.z*v1.z + v1.w*v1.w);
    *(uint4*)&xo[f] = cvt8(v0, v1);
  }
  #pragma unroll
  for (int o = 1; o < 64; o <<= 1) { s += __shfl_xor(s, o); q += __shfl_xor(q, o); }
  __shared__ float red[8];
  int wave = t >> 6, lane = t & 63;
  if (lane == 0) { red[wave*2] = s; red[wave*2+1] = q; }
  __syncthreads();
  if (t == 0) {
    part[c*2]   = red[0] + red[2] + red[4] + red[6];
    part[c*2+1] = red[1] + red[3] + red[5] + red[7];
  }
}

// ---- once per segment: finalize stats1 + fold GN1 bias through all 384 W columns + alpha scales
__global__ __launch_bounds__(384) void k_prep2(
    const float* __restrict__ part, const float* __restrict__ Wqkv,
    const float* __restrict__ gn1w, const float* __restrict__ gn1b,
    float* __restrict__ biasv, float* __restrict__ alpha)
{
  __shared__ float red[8];
  __shared__ float sm[2];
  const int seg = blockIdx.x, t = threadIdx.x;   // 384 threads
  const int wave = t >> 6, lane = t & 63;
  if (t < 256) {
    float s = part[(seg*256 + t)*2], q = part[(seg*256 + t)*2 + 1];
    #pragma unroll
    for (int o = 1; o < 64; o <<= 1) { s += __shfl_xor(s, o); q += __shfl_xor(q, o); }
    if (lane == 0) { red[wave*2] = s; red[wave*2+1] = q; }
  }
  __syncthreads();
  if (t == 0) {
    float s = red[0] + red[2] + red[4] + red[6];
    float q = red[1] + red[3] + red[5] + red[7];
    float mu = s * INVN;
    float var = q * INVN - mu * mu;
    float rs = rsqrtf(var + EPS_GN);
    sm[0] = mu * rs; sm[1] = rs;
  }
  __syncthreads();
  const float mu_rs = sm[0], rs = sm[1];
  float s = 0.f;
  for (int ch = 0; ch < 128; ++ch)
    s += (gn1b[ch] - mu_rs * gn1w[ch]) * Wqkv[ch * 384 + t];
  float scale = (t < 128) ? QSCALE : ((t < 256) ? KSCALE : 1.f);
  biasv[seg*384 + t] = s * scale;
  if (t == 0) {
    alpha[seg*4]   = rs * QSCALE;
    alpha[seg*4+1] = rs * KSCALE;
    alpha[seg*4+2] = rs;
  }
}

// ---- k,v GEMM + exp(k) -> sum_e, ctx += E^T@V. 512 blocks x 256 thr (4 waves = 4 heads).
//      4-deep load pipeline, no prologue.
__global__ __launch_bounds__(256, 2) void k_kv(
    const unsigned short* __restrict__ xb, const unsigned short* __restrict__ WT,
    const float* __restrict__ biasv, const float* __restrict__ alpha,
    float* __restrict__ sume_p, float* __restrict__ ctx_p)
{
  const int t = threadIdx.x;
  const int h = t >> 6, lane = t & 63;
  const int lm = lane & 15, lg = lane >> 4;
  const int bid = blockIdx.x;               // 512 = 8 seg * 64 sub
  const int seg = bid >> 6, sub = bid & 63;

  const float alk = alpha[seg*4 + 1], alv = alpha[seg*4 + 2];
  const float ck0 = biasv[seg*384 + 128 + h*32 + lm];
  const float ck1 = biasv[seg*384 + 128 + h*32 + 16 + lm];
  const float cv0 = biasv[seg*384 + 256 + h*32 + lm];
  const float cv1 = biasv[seg*384 + 256 + h*32 + 16 + lm];

  bf16x8 wk[2][4], wv[2][4];
  #pragma unroll
  for (int nt = 0; nt < 2; ++nt)
    #pragma unroll
    for (int kk = 0; kk < 4; ++kk) {
      int row = h*32 + nt*16 + lm;
      wk[nt][kk] = *(const bf16x8*)&WT[(row + 128) * 128 + kk*32 + lg*8];
      wv[nt][kk] = *(const bf16x8*)&WT[(row + 256) * 128 + kk*32 + lg*8];
    }

  f32x4 ctx00 = {0,0,0,0}, ctx01 = {0,0,0,0}, ctx10 = {0,0,0,0}, ctx11 = {0,0,0,0};
  float se0 = 0.f, se1 = 0.f;

  const unsigned short* xw = xb + (size_t)(seg * LSEG + sub*512 + lm) * 128 + lg*8;

#define ISSUE(S, IT) { \
    const unsigned short* p_ = xw + (size_t)((IT) * 16) * 128; \
    S[0] = *(const bf16x8*)(p_);      \
    S[1] = *(const bf16x8*)(p_ + 32); \
    S[2] = *(const bf16x8*)(p_ + 64); \
    S[3] = *(const bf16x8*)(p_ + 96); }

#define COMPUTE(S) { \
    f32x4 ka0 = {0,0,0,0}, ka1 = {0,0,0,0}, va0 = {0,0,0,0}, va1 = {0,0,0,0}; \
    _Pragma("unroll") for (int kk = 0; kk < 4; ++kk) { \
      ka0 = MFMA32(S[kk], wk[0][kk], ka0); \
      ka1 = MFMA32(S[kk], wk[1][kk], ka1); \
    } \
    _Pragma("unroll") for (int kk = 0; kk < 4; ++kk) { \
      va0 = MFMA32(S[kk], wv[0][kk], va0); \
      va1 = MFMA32(S[kk], wv[1][kk], va1); \
    } \
    float e_[8]; \
    _Pragma("unroll") for (int r = 0; r < 4; ++r) { \
      e_[r]     = __expf(fmaf(ka0[r], alk, ck0)); \
      e_[4 + r] = __expf(fmaf(ka1[r], alk, ck1)); \
    } \
    se0 += (e_[0] + e_[1]) + (e_[2] + e_[3]); \
    se1 += (e_[4] + e_[5]) + (e_[6] + e_[7]); \
    s16x4 E0 = pack4(e_[0], e_[1], e_[2], e_[3]); \
    s16x4 E1 = pack4(e_[4], e_[5], e_[6], e_[7]); \
    s16x4 V0 = pack4(fmaf(va0[0], alv, cv0), fmaf(va0[1], alv, cv0), \
                     fmaf(va0[2], alv, cv0), fmaf(va0[3], alv, cv0)); \
    s16x4 V1 = pack4(fmaf(va1[0], alv, cv1), fmaf(va1[1], alv, cv1), \
                     fmaf(va1[2], alv, cv1), fmaf(va1[3], alv, cv1)); \
    ctx00 = MFMA16(E0, V0, ctx00); \
    ctx01 = MFMA16(E0, V1, ctx01); \
    ctx10 = MFMA16(E1, V0, ctx10); \
    ctx11 = MFMA16(E1, V1, ctx11); }

  bf16x8 sA[4], sB[4], sC[4], sD[4];
  ISSUE(sA, 0);
  ISSUE(sB, 1);
  #pragma unroll 1
  for (int it = 0; it < 32; it += 4) {
    ISSUE(sC, it + 2);
    COMPUTE(sA);
    ISSUE(sD, it + 3);
    COMPUTE(sB);
    if (it + 4 < 32) ISSUE(sA, it + 4);
    COMPUTE(sC);
    if (it + 5 < 32) ISSUE(sB, it + 5);
    COMPUTE(sD);
  }
#undef ISSUE
#undef COMPUTE

  se0 += __shfl_xor(se0, 16); se0 += __shfl_xor(se0, 32);
  se1 += __shfl_xor(se1, 16); se1 += __shfl_xor(se1, 32);
  if (lane < 16) {
    sume_p[(size_t)bid*128 + h*32 + lm]      = se0;
    sume_p[(size_t)bid*128 + h*32 + 16 + lm] = se1;
  }
  float* cp = ctx_p + (size_t)bid*4096 + h*1024;
  #pragma unroll
  for (int r = 0; r < 4; ++r) {
    cp[(lg*4 + r)*32      + lm]      = ctx00[r];
    cp[(lg*4 + r)*32      + 16 + lm] = ctx01[r];
    cp[(16 + lg*4 + r)*32 + lm]      = ctx10[r];
    cp[(16 + lg*4 + r)*32 + 16 + lm] = ctx11[r];
  }
}

// ---- reduce ctx partials, normalize, fold Wc = blockdiag(ctx)@W_out -> WcT[seg][oc][qc] bf16
__global__ __launch_bounds__(256) void k_wc(
    const float* __restrict__ sume_p, const float* __restrict__ ctx_p,
    const float* __restrict__ Wout, unsigned short* __restrict__ WcT)
{
  __shared__ float sctx[1024];
  __shared__ float sse[32];
  const int t = threadIdx.x, b = blockIdx.x;
  const int seg = b >> 5, head = (b >> 3) & 3, ocg = b & 7;
  float acc[4] = {0.f, 0.f, 0.f, 0.f};
  for (int j = 0; j < 64; ++j) {
    const float* cp = ctx_p + (size_t)(seg*64 + j)*4096 + head*1024;
    #pragma unroll
    for (int e = 0; e < 4; ++e) acc[e] += cp[t + e*256];
  }
  if (t < 32) {
    float s = 0.f;
    for (int j = 0; j < 64; ++j) s += sume_p[(size_t)(seg*64 + j)*128 + head*32 + t];
    sse[t] = s;
  }
  #pragma unroll
  for (int e = 0; e < 4; ++e) sctx[t + e*256] = acc[e];
  __syncthreads();
  #pragma unroll
  for (int e = 0; e < 2; ++e) {
    int idx = t + e*256;              // 512 outputs: 32 kc x 16 oc
    int kc = idx >> 4, ocl = idx & 15;
    int oc = ocg*16 + ocl;
    float s = 0.f;
    #pragma unroll
    for (int vc = 0; vc < 32; ++vc)
      s += sctx[kc*32 + vc] * Wout[(head*32 + vc)*128 + oc];
    WcT[((size_t)seg*128 + oc)*128 + head*32 + kc] = f2bf(s / sse[kc]);
  }
}

// ---- q recompute -> softmax -> P LDS exchange -> out GEMM -> staged bf16 store + stats2 partials.
//      512 blocks x 256 thr (4 waves = 4 heads), 512 pts each. Loads one full phase ahead.
__global__ __launch_bounds__(256, 2) void k_out3(
    const unsigned short* __restrict__ xb, const unsigned short* __restrict__ WT,
    const float* __restrict__ biasv, const float* __restrict__ alpha,
    const unsigned short* __restrict__ WcT,
    float* __restrict__ part2, unsigned short* __restrict__ outm)
{
  __shared__ float red8[8];
  __shared__ __attribute__((aligned(16))) short pbuf[2][8 * 256];               // P exchange, dbuf
  __shared__ __attribute__((aligned(16))) unsigned short sou[2][16 * SOPITCH];  // out staging, dbuf

  const int t = threadIdx.x;
  const int w = t >> 6, lane = t & 63;
  const int lm = lane & 15, lg = lane >> 4;
  const int bid = blockIdx.x;               // 512 = 8 seg * 64 sub
  const int seg = bid >> 6;
  const size_t cb = (size_t)bid * 512;

  const float alq = alpha[seg*4];
  const float4 cq0 = *(const float4*)&biasv[seg*384 + w*32 + lg*4];
  const float4 cq1 = *(const float4*)&biasv[seg*384 + w*32 + 16 + lg*4];

  bf16x8 wq[2][4];
  #pragma unroll
  for (int nt = 0; nt < 2; ++nt)
    #pragma unroll
    for (int kk = 0; kk < 4; ++kk)
      wq[nt][kk] = *(const bf16x8*)&WT[(w*32 + nt*16 + lm) * 128 + kk*32 + lg*8];
  s16x4 wc[2][8];
  #pragma unroll
  for (int o = 0; o < 2; ++o)
    #pragma unroll
    for (int kt = 0; kt < 8; ++kt)
      wc[o][kt] = *(const s16x4*)&WcT[((size_t)seg*128 + (w*32 + o*16 + lm))*128 + kt*16 + lg*4];

  const unsigned short* xw = xb + (cb + lm) * 128 + lg*8;
  float ssum = 0.f, ssq = 0.f;
  bf16x8 xa0, xa1, xa2, xa3;   // phase-A prefetch set
  bf16x8 xb0, xb1, xb2, xb3;   // phase-B prefetch set

#define LOADA(IT) { \
    const unsigned short* p_ = xw + (size_t)((IT) * 16) * 128; \
    xa0 = *(const bf16x8*)(p_);      \
    xa1 = *(const bf16x8*)(p_ + 32); \
    xa2 = *(const bf16x8*)(p_ + 64); \
    xa3 = *(const bf16x8*)(p_ + 96); }

#define LOADB(IT) { \
    const unsigned short* p_ = xw + (size_t)((IT) * 16) * 128; \
    xb0 = *(const bf16x8*)(p_);      \
    xb1 = *(const bf16x8*)(p_ + 32); \
    xb2 = *(const bf16x8*)(p_ + 64); \
    xb3 = *(const bf16x8*)(p_ + 96); }

#define SM2P_X(D, X0, X1, X2, X3) { \
    f32x4 qa0 = {0,0,0,0}, qa1 = {0,0,0,0}; \
    qa0 = MFMA32(wq[0][0], X0, qa0); qa1 = MFMA32(wq[1][0], X0, qa1); \
    qa0 = MFMA32(wq[0][1], X1, qa0); qa1 = MFMA32(wq[1][1], X1, qa1); \
    qa0 = MFMA32(wq[0][2], X2, qa0); qa1 = MFMA32(wq[1][2], X2, qa1); \
    qa0 = MFMA32(wq[0][3], X3, qa0); qa1 = MFMA32(wq[1][3], X3, qa1); \
    float a_[8]; \
    _Pragma("unroll") for (int r = 0; r < 4; ++r) { \
      a_[r]     = fmaf(qa0[r], alq, ((const float*)&cq0)[r]); \
      a_[4 + r] = fmaf(qa1[r], alq, ((const float*)&cq1)[r]); \
    } \
    float m_ = a_[0]; \
    _Pragma("unroll") for (int i = 1; i < 8; ++i) m_ = fmaxf(m_, a_[i]); \
    m_ = fmaxf(m_, __shfl_xor(m_, 16)); \
    m_ = fmaxf(m_, __shfl_xor(m_, 32)); \
    float s_ = 0.f; \
    _Pragma("unroll") for (int i = 0; i < 8; ++i) { a_[i] = __expf(a_[i] - m_); s_ += a_[i]; } \
    s_ += __shfl_xor(s_, 16); \
    s_ += __shfl_xor(s_, 32); \
    float inv_ = 1.f / s_; \
    *(s16x4*)&pbuf[D][(w*2)*256 + lane*4]     = pack4(a_[0]*inv_, a_[1]*inv_, a_[2]*inv_, a_[3]*inv_); \
    *(s16x4*)&pbuf[D][(w*2 + 1)*256 + lane*4] = pack4(a_[4]*inv_, a_[5]*inv_, a_[6]*inv_, a_[7]*inv_); }

#define GEMMSTORE(D, IA) { \
    f32x4 acc0 = {0,0,0,0}, acc1 = {0,0,0,0}; \
    _Pragma("unroll") \
    for (int kt = 0; kt < 8; ++kt) { \
      s16x4 pk = *(const s16x4*)&pbuf[D][kt*256 + lane*4]; \
      acc0 = MFMA16(wc[0][kt], pk, acc0); \
      acc1 = MFMA16(wc[1][kt], pk, acc1); \
    } \
    if ((IA) > 0) { \
      int f = 2*t; \
      int pt = f >> 5, cc = f & 31; \
      *(uint4*)((ushort4*)outm + (cb + (size_t)((IA)-1)*16 + pt)*32 + cc) = \
          *(const uint4*)&sou[(D)^1][pt*SOPITCH + cc*4]; \
    } \
    _Pragma("unroll") \
    for (int r = 0; r < 4; ++r) { \
      ssum += acc0[r] + acc1[r]; \
      ssq  += acc0[r]*acc0[r] + acc1[r]*acc1[r]; \
    } \
    { \
      short* dst = (short*)&sou[D][lm*SOPITCH + w*32 + lg*4]; \
      *(s16x4*)dst        = pack4(acc0[0], acc0[1], acc0[2], acc0[3]); \
      *(s16x4*)(dst + 16) = pack4(acc1[0], acc1[1], acc1[2], acc1[3]); \
    } }

  LOADA(0);
  SM2P_X(0, xa0, xa1, xa2, xa3);      // P(0) -> pbuf[0] (only prologue stall)
  LOADB(1);                           // tile 1 in flight across phase 0

  #pragma unroll 1
  for (int ia = 0; ia < 32; ia += 2) {
    __syncthreads();                  // pbuf[0]=P(ia) ready; sou[1]=out(ia-1) ready
    if (ia + 2 < 32) LOADA(ia + 2);   // in flight across this whole phase
    GEMMSTORE(0, ia);                 // GEMM tile ia; store tile ia-1; stage sou[0]=out(ia)
    SM2P_X(1, xb0, xb1, xb2, xb3);    // P(ia+1): loads issued one full phase ago
    __syncthreads();                  // pbuf[1]=P(ia+1) ready; sou[0]=out(ia) ready
    if (ia + 3 < 32) LOADB(ia + 3);
    GEMMSTORE(1, ia + 1);             // GEMM tile ia+1; store tile ia; stage sou[1]=out(ia+1)
    if (ia + 2 < 32) SM2P_X(0, xa0, xa1, xa2, xa3);  // P(ia+2)
  }
  __syncthreads();
  // tail: store tile 31 (in sou[1])
  {
    int f = 2*t;
    int pt = f >> 5, cc = f & 31;
    *(uint4*)((ushort4*)outm + (cb + (size_t)31*16 + pt)*32 + cc) =
        *(const uint4*)&sou[1][pt*SOPITCH + cc*4];
  }
#undef LOADA
#undef LOADB
#undef SM2P_X
#undef GEMMSTORE

  #pragma unroll
  for (int o = 1; o < 64; o <<= 1) { ssum += __shfl_xor(ssum, o); ssq += __shfl_xor(ssq, o); }
  if (lane == 0) { red8[w*2] = ssum; red8[w*2+1] = ssq; }
  __syncthreads();
  if (t == 0) {
    part2[bid*2]   = red8[0] + red8[2] + red8[4] + red8[6];
    part2[bid*2+1] = red8[1] + red8[3] + red8[5] + red8[7];
  }
}

// ---- GN2 (stats from part2: 64 partials/seg) + residual; 16B paired loads, 32B stores (nontemporal y)
__global__ __launch_bounds__(256) void k_fin(
    const unsigned short* __restrict__ xb, const unsigned short* __restrict__ out_ws,
    const float* __restrict__ part2, const float* __restrict__ gn2w, const float* __restrict__ gn2b,
    float* __restrict__ y)
{
  __shared__ float sm[2];
  const int t = threadIdx.x;
  const int b = blockIdx.x >> 8, blk = blockIdx.x & 255;
  if (t < 64) {
    float s = part2[(b*64 + t)*2], q = part2[(b*64 + t)*2 + 1];
    #pragma unroll
    for (int o = 1; o < 64; o <<= 1) { s += __shfl_xor(s, o); q += __shfl_xor(q, o); }
    if (t == 0) {
      float mu = s * INVN;
      float var = q * INVN - mu * mu;
      sm[0] = mu; sm[1] = rsqrtf(var + EPS_GN);
    }
  }
  __syncthreads();
  const float mu = sm[0], rs = sm[1];
  const int c8 = (t & 15) * 8;
  const float4 w4a = *(const float4*)&gn2w[c8];
  const float4 w4b = *(const float4*)&gn2w[c8 + 4];
  const float4 g4a = *(const float4*)&gn2b[c8];
  const float4 g4b = *(const float4*)&gn2b[c8 + 4];
  const size_t base = (size_t)b * 1048576 + (size_t)blk * 4096;
  const ushort4* xp = (const ushort4*)xb + base;
  const ushort4* op = (const ushort4*)out_ws + base;
  f32x4* yp = (f32x4*)y + base;
  #pragma unroll
  for (int k = 0; k < 8; ++k) {
    int f = 2*t + 512*k;
    uint4 xu = *(const uint4*)&xp[f];
    uint4 ou = *(const uint4*)&op[f];
    f32x4 r0, r1;
    r0[0] = (__uint_as_float(ou.x << 16)          - mu) * rs * w4a.x + g4a.x + __uint_as_float(xu.x << 16);
    r0[1] = (__uint_as_float(ou.x & 0xffff0000u)  - mu) * rs * w4a.y + g4a.y + __uint_as_float(xu.x & 0xffff0000u);
    r0[2] = (__uint_as_float(ou.y << 16)          - mu) * rs * w4a.z + g4a.z + __uint_as_float(xu.y << 16);
    r0[3] = (__uint_as_float(ou.y & 0xffff0000u)  - mu) * rs * w4a.w + g4a.w + __uint_as_float(xu.y & 0xffff0000u);
    r1[0] = (__uint_as_float(ou.z << 16)          - mu) * rs * w4b.x + g4b.x + __uint_as_float(xu.z << 16);
    r1[1] = (__uint_as_float(ou.z & 0xffff0000u)  - mu) * rs * w4b.y + g4b.y + __uint_as_float(xu.z & 0xffff0000u);
    r1[2] = (__uint_as_float(ou.w << 16)          - mu) * rs * w4b.z + g4b.z + __uint_as_float(xu.w << 16);
    r1[3] = (__uint_as_float(ou.w & 0xffff0000u)  - mu) * rs * w4b.w + g4b.w + __uint_as_float(xu.w & 0xffff0000u);
    __builtin_nontemporal_store(r0, &yp[f]);
    __builtin_nontemporal_store(r1, &yp[f + 1]);
  }
}

extern "C" void kernel_launch(void* const* d_in, const int* in_sizes, int n_in,
                              void* d_out, int out_size, void* d_ws, size_t ws_size,
                              hipStream_t stream) {
  const float* x    = (const float*)d_in[0];
  const float* gn1w = (const float*)d_in[1];
  const float* gn1b = (const float*)d_in[2];
  const float* Wqkv = (const float*)d_in[3];
  const float* Wout = (const float*)d_in[4];
  const float* gn2w = (const float*)d_in[5];
  const float* gn2b = (const float*)d_in[6];
  float* y = (float*)d_out;
  char* ws = (char*)d_ws;

  float*          part   = (float*)(ws + 0);                 // 2048*2 f32 = 16384
  float*          part2  = (float*)(ws + 16384);             // 512*2 f32 = 4096
  unsigned short* WT     = (unsigned short*)(ws + 24576);    // 384*128 bf16 = 98304
  unsigned short* WcT    = (unsigned short*)(ws + 122880);   // 8*128*128 bf16 = 262144
  float*          biasv  = (float*)(ws + 385024);            // 8*384 f32 = 12288
  float*          alphav = (float*)(ws + 397312);            // 8*4 f32
  float*          sume_p = (float*)(ws + 401408);            // 512*128 f32 = 262144
  float*          ctx_p  = (float*)(ws + 663552);            // 512*4096 f32 = 8388608
  unsigned short* xb     = (unsigned short*)(ws + 9052160);  // 67108864
  unsigned short* outm   = (unsigned short*)(ws + 76161024); // 67108864

  hipLaunchKernelGGL(k_pre,   dim3(2240), dim3(256), 0, stream, x, part, xb, Wqkv, gn1w, WT);
  hipLaunchKernelGGL(k_prep2, dim3(8),    dim3(384), 0, stream, part, Wqkv, gn1w, gn1b, biasv, alphav);
  hipLaunchKernelGGL(k_kv,    dim3(512),  dim3(256), 0, stream, xb, WT, biasv, alphav, sume_p, ctx_p);
  hipLaunchKernelGGL(k_wc,    dim3(256),  dim3(256), 0, stream, sume_p, ctx_p, Wout, WcT);
  hipLaunchKernelGGL(k_out3,  dim3(512),  dim3(256), 0, stream, xb, WT, biasv, alphav, WcT, part2, outm);
  hipLaunchKernelGGL(k_fin,   dim3(2048), dim3(256), 0, stream, xb, outm, part2, gn2w, gn2b, y);
}